// Round 7
// baseline (117.881 us; speedup 1.0000x reference)
//
#include <hip/hip_runtime.h>

typedef unsigned short u16;
typedef unsigned int u32;
typedef __attribute__((ext_vector_type(8))) __bf16 bf16x8;
typedef __attribute__((ext_vector_type(4))) float f32x4;
typedef __attribute__((ext_vector_type(4))) u16 u16x4;

#define MFMA16(a, b, c) __builtin_amdgcn_mfma_f32_16x16x32_bf16((a), (b), (c), 0, 0, 0)

static __device__ __forceinline__ u16 f2b(float f) {
  union { float f; u32 u; } v; v.f = f;
  u32 u = v.u;
  return (u16)((u + 0x7FFFu + ((u >> 16) & 1u)) >> 16);
}

static __device__ __forceinline__ float b2f(u16 s) {
  union { u32 u; float f; } c; c.u = (u32)s << 16; return c.f;
}

// packed f32x2 -> bf16x2 (RNE), low half = a
static __device__ __forceinline__ u32 pack2(float a, float b) {
  u32 r;
  asm("v_cvt_pk_bf16_f32 %0, %1, %2" : "=v"(r) : "v"(a), "v"(b));
  return r;
}

static __device__ __forceinline__ float exp2fast(float x) {
#if defined(__has_builtin) && __has_builtin(__builtin_amdgcn_exp2f)
  return __builtin_amdgcn_exp2f(x);
#else
  return __expf(x * 0.6931471805599453f);
#endif
}

static __device__ __forceinline__ void gload16(const u16* gp, u16* lp) {
  __builtin_amdgcn_global_load_lds((__attribute__((address_space(1))) void*)(u16*)gp,
                                   (__attribute__((address_space(3))) void*)lp, 16, 0, 0);
}

// ---------------- merged prep kernel ----------------
__global__ __launch_bounds__(256) void k_prep(const float* __restrict__ Wqkv, const float* __restrict__ Wout,
                                              const float* __restrict__ W1p, const float* __restrict__ W2p,
                                              const float* __restrict__ x,
                                              u16* __restrict__ WB, u16* __restrict__ WoT,
                                              u16* __restrict__ xb) {
  const int b = blockIdx.x;
  const int t = threadIdx.x;
  if (b < 4096) {
    __shared__ float tile[32][33];
    const float* src; u16* dst; int N, n0, k0;
    if (b < 3072) { src = Wqkv; dst = WB;  N = 3072; n0 = (b % 96) * 32; k0 = (b / 96) * 32; }
    else { const int bb = b - 3072; src = Wout; dst = WoT; N = 1024; n0 = (bb & 31) * 32; k0 = (bb >> 5) * 32; }
    const int r = t >> 3, c4 = (t & 7) << 2;
    const float4 in4 = *(const float4*)(src + (size_t)(k0 + r) * N + n0 + c4);
    tile[r][c4 + 0] = in4.x; tile[r][c4 + 1] = in4.y;
    tile[r][c4 + 2] = in4.z; tile[r][c4 + 3] = in4.w;
    __syncthreads();
    u16x4 o;
    o.x = f2b(tile[c4 + 0][r]); o.y = f2b(tile[c4 + 1][r]);
    o.z = f2b(tile[c4 + 2][r]); o.w = f2b(tile[c4 + 3][r]);
    *(u16x4*)(dst + (size_t)(n0 + r) * 1024 + k0 + c4) = o;
  } else if (b < 4608) {
    const int idx = (b - 4096) * 256 + t;  // 131072
    const int j = idx >> 10, k = idx & 1023;
    const float v = (j < 64) ? W1p[(size_t)k * 64 + j] : W2p[(size_t)k * 64 + (j - 64)];
    WB[(size_t)3072 * 1024 + idx] = f2b(v);
  } else {
    const size_t idx = ((size_t)(b - 4608) * 256 + t) << 2;
    const float4 v = *(const float4*)(x + idx);
    u16x4 o; o.x = f2b(v.x); o.y = f2b(v.y); o.z = f2b(v.z); o.w = f2b(v.w);
    *(u16x4*)(xb + idx) = o;
  }
}

// ---------------- 128x64 bf16 MFMA GEMM core (BK=64, global_load_lds, XOR swizzle) ----------------
static __device__ __forceinline__ void gemm_core_128x64(const u16* __restrict__ A, const u16* __restrict__ B,
                                                        int brow, int bcol, int K,
                                                        u16* ldsA, u16* ldsB, f32x4 acc[4][2]) {
  const int tid = threadIdx.x;
  const int wave = tid >> 6, lane = tid & 63;
  const int wr = wave >> 1, wc = wave & 1;
  const int g = lane >> 4, l15 = lane & 15;

  for (int k0 = 0; k0 < K; k0 += 64) {
#pragma unroll
    for (int li = 0; li < 4; ++li) {
      const int f = li * 256 + wave * 64 + lane;
      const int row = f >> 3;
      const int slot = f & 7;
      const int gcol = ((slot ^ (row & 7)) << 3);
      gload16(A + (size_t)(brow + row) * K + k0 + gcol, ldsA + (size_t)(li * 256 + wave * 64) * 8);
    }
#pragma unroll
    for (int li = 0; li < 2; ++li) {
      const int f = li * 256 + wave * 64 + lane;
      const int row = f >> 3;
      const int slot = f & 7;
      const int gcol = ((slot ^ (row & 7)) << 3);
      gload16(B + (size_t)(bcol + row) * K + k0 + gcol, ldsB + (size_t)(li * 256 + wave * 64) * 8);
    }
    __syncthreads();
    bf16x8 af[4][2], bfr[2][2];
#pragma unroll
    for (int kk = 0; kk < 2; ++kk) {
#pragma unroll
      for (int m = 0; m < 4; ++m) {
        const int rowA = wr * 64 + m * 16 + l15;
        const int chA = (kk * 4 + g) ^ (rowA & 7);
        af[m][kk] = *(const bf16x8*)(ldsA + (size_t)rowA * 64 + chA * 8);
      }
#pragma unroll
      for (int n = 0; n < 2; ++n) {
        const int rowB = wc * 32 + n * 16 + l15;
        const int chB = (kk * 4 + g) ^ (rowB & 7);
        bfr[n][kk] = *(const bf16x8*)(ldsB + (size_t)rowB * 64 + chB * 8);
      }
    }
#pragma unroll
    for (int m = 0; m < 4; ++m)
#pragma unroll
      for (int n = 0; n < 2; ++n)
#pragma unroll
        for (int kk = 0; kk < 2; ++kk)
          acc[m][n] = MFMA16(af[m][kk], bfr[n][kk], acc[m][n]);
    __syncthreads();
  }
}

// ---------------- GEMM1: x @ [Wqkv|W1p|W2p]  (M=2048, N=3200, K=1024) ----------------
__global__ __launch_bounds__(256) void k_gemm_qkvp(const u16* __restrict__ xb, const u16* __restrict__ WB,
                                                   const float* __restrict__ bqkv,
                                                   u16* __restrict__ Qext, u16* __restrict__ Kext,
                                                   u16* __restrict__ Vt, float* __restrict__ P12) {
  __shared__ __align__(16) u16 ldsA[128 * 64];
  __shared__ __align__(16) u16 ldsB[64 * 64];
  const int bid = blockIdx.x;                      // 800 blocks
  const int bn = bid % 50, bm = bid / 50;
  f32x4 acc[4][2];
#pragma unroll
  for (int m = 0; m < 4; ++m)
#pragma unroll
    for (int n = 0; n < 2; ++n) acc[m][n] = (f32x4){0.f, 0.f, 0.f, 0.f};
  gemm_core_128x64(xb, WB, bm * 128, bn * 64, 1024, ldsA, ldsB, acc);

  const int tid = threadIdx.x;
  const int wave = tid >> 6, lane = tid & 63;
  const int wr = wave >> 1, wc = wave & 1;
  const int g = lane >> 4, l15 = lane & 15;
  const int tbase = bm * 128 + wr * 64 + g * 4;
  const int cbase = bn * 64 + wc * 32 + l15;
#pragma unroll
  for (int m = 0; m < 4; ++m) {
#pragma unroll
    for (int n = 0; n < 2; ++n) {
      const int c = cbase + n * 16;
#pragma unroll
      for (int r = 0; r < 4; ++r) {
        const int t = tbase + m * 16 + r;
        float v = acc[m][n][r];
        if (c < 3072) {
          v += bqkv[c];
          const int sub = c >> 10;
          const int rem = c & 1023;
          const int hh = rem >> 6, d = rem & 63;
          if (sub == 0)      Qext[((size_t)hh * 2048 + t) * 96 + d] = f2b(v * 0.18033688f);
          else if (sub == 1) Kext[((size_t)hh * 2048 + t) * 96 + d] = f2b(v);
          else               Vt[((size_t)hh * 64 + d) * 2048 + t] = f2b(v);
        } else {
          P12[(size_t)t * 128 + (c - 3072)] = v;
        }
      }
    }
  }
}

// ---------------- Plucker lines -> Qext/Kext cols 64..95 ----------------
__global__ __launch_bounds__(256) void k_lines(const float* __restrict__ P12, const float* __restrict__ pscale,
                                               u16* __restrict__ Qext, u16* __restrict__ Kext) {
  const int idx = blockIdx.x * 256 + threadIdx.x;  // 32768 = 2048*16
  const int t = idx >> 4, h = idx & 15;
  const float* p = P12 + (size_t)t * 128;
  const float a0 = p[h * 4 + 0], a1 = p[h * 4 + 1], a2 = p[h * 4 + 2], a3 = p[h * 4 + 3];
  const float b0 = p[64 + h * 4 + 0], b1 = p[64 + h * 4 + 1], b2 = p[64 + h * 4 + 2], b3 = p[64 + h * 4 + 3];
  float L0 = a0 * b1 - a1 * b0;
  float L1 = a0 * b2 - a2 * b0;
  float L2 = a0 * b3 - a3 * b0;
  float L3 = a1 * b2 - a2 * b1;
  float L4 = a1 * b3 - a3 * b1;
  float L5 = a2 * b3 - a3 * b2;
  const float nrm = sqrtf(L0 * L0 + L1 * L1 + L2 * L2 + L3 * L3 + L4 * L4 + L5 * L5);
  const float inv = 1.0f / fmaxf(nrm, 1e-12f);
  L0 *= inv; L1 *= inv; L2 *= inv; L3 *= inv; L4 *= inv; L5 *= inv;
  const float s = pscale[h] * 1.44269504f;  // fold log2(e) into q-side bias
  u16* q = Qext + ((size_t)h * 2048 + t) * 96 + 64;
  u16* k = Kext + ((size_t)h * 2048 + t) * 96 + 64;
  q[0] = f2b(L0 * s); q[1] = f2b(L1 * s); q[2] = f2b(L2 * s);
  q[3] = f2b(L3 * s); q[4] = f2b(L4 * s); q[5] = f2b(L5 * s);
  // Jlines = J6 @ L : [L5, -L4, L3, L2, -L1, L0]
  k[0] = f2b(L5); k[1] = f2b(-L4); k[2] = f2b(L3);
  k[3] = f2b(L2); k[4] = f2b(-L1); k[5] = f2b(L0);
#pragma unroll
  for (int c = 6; c < 32; ++c) { q[c] = 0; k[c] = 0; }
}

// ---------------- fused causal attention: paired dual-stream + split-KV x2 ----------------
// Wave = (head, pair p, split s). Pair owns q-tiles A=p, B=127-p; steps jt in [jBeg,jEnd):
// split0 [0,mid), split1 [mid,sB), mid=sB/2. K/V loads shared between streams; no-max exp2
// softmax -> split partials combine by PURE ADDITION in k_comb. 2048 waves = 2/SIMD TLP.
__global__ __launch_bounds__(64) void k_attn(const u16* __restrict__ Qext, const u16* __restrict__ Kext,
                                             const u16* __restrict__ Vt,
                                             u16* __restrict__ Op0, u16* __restrict__ Op1,
                                             float* __restrict__ lp0, float* __restrict__ lp1,
                                             int nsplit) {
  const int bid = blockIdx.x;                     // 1024*nsplit blocks
  const int split = bid >> 10;
  const int h = bid & 15;
  const int p = (bid >> 4) & 63;
  const int lane = threadIdx.x;
  const int g = lane >> 4, l15 = lane & 15;
  const int q0A = p << 4;
  const int q0B = (127 - p) << 4;
  const int qgA = q0A + l15;
  const int qgB = q0B + l15;
  const int sA = (p >> 1) + 1;                    // steps where stream A is active
  const int sB = ((127 - p) >> 1) + 1;            // total steps (>= sA)
  const int mid = sB >> 1;
  const int jBeg = (nsplit == 2 && split) ? mid : 0;
  const int jEnd = (nsplit == 2 && !split) ? mid : sB;
  const u16* Qh = Qext + (size_t)h * 2048 * 96;
  const u16* Kh = Kext + (size_t)h * 2048 * 96;
  const u16* Vh = Vt + (size_t)h * 64 * 2048;

  bf16x8 aqA[3], aqB[3];
#pragma unroll
  for (int ks = 0; ks < 3; ++ks) {
    aqA[ks] = *(const bf16x8*)(Qh + (size_t)qgA * 96 + ks * 32 + g * 8);
    aqB[ks] = *(const bf16x8*)(Qh + (size_t)qgB * 96 + ks * 32 + g * 8);
  }

  f32x4 accA[4], accB[4];
#pragma unroll
  for (int n = 0; n < 4; ++n) {
    accA[n] = (f32x4){0.f, 0.f, 0.f, 0.f};
    accB[n] = (f32x4){0.f, 0.f, 0.f, 0.f};
  }
  float lA = 0.f, lB = 0.f;

  const u16* Kbase = Kh + (size_t)l15 * 96 + g * 8;
  const int src0 = ((g & 1) << 5) + l15;
  const int src1 = src0 + 16;

  bf16x8 kX0[3], kX1[3], kY0[3], kY1[3];

#define GLUE(S0, S1, Q0S, QGS, LS, PBS)                                           \
  {                                                                               \
    if (jb + 31 > Q0S) {                                                          \
      _Pragma("unroll")                                                           \
      for (int r = 0; r < 4; ++r) {                                               \
        if (jb + g * 4 + r > QGS) S0[r] = -1e30f;                                 \
        if (jb + 16 + g * 4 + r > QGS) S1[r] = -1e30f;                            \
      }                                                                           \
    }                                                                             \
    _Pragma("unroll")                                                             \
    for (int r = 0; r < 4; ++r) {                                                 \
      S0[r] = exp2fast(S0[r]);                                                    \
      S1[r] = exp2fast(S1[r]);                                                    \
    }                                                                             \
    LS += ((S0[0] + S0[1]) + (S0[2] + S0[3])) + ((S1[0] + S1[1]) + (S1[2] + S1[3])); \
    const u32 w0 = pack2(S0[0], S0[1]);                                           \
    const u32 w1 = pack2(S0[2], S0[3]);                                           \
    const u32 w2 = pack2(S1[0], S1[1]);                                           \
    const u32 w3 = pack2(S1[2], S1[3]);                                           \
    const u32 a0 = (u32)__shfl((int)w0, src0);                                    \
    const u32 a1 = (u32)__shfl((int)w2, src0);                                    \
    const u32 b0 = (u32)__shfl((int)w1, src0);                                    \
    const u32 b1 = (u32)__shfl((int)w3, src0);                                    \
    const u32 c0 = (u32)__shfl((int)w0, src1);                                    \
    const u32 c1 = (u32)__shfl((int)w2, src1);                                    \
    const u32 d0 = (u32)__shfl((int)w1, src1);                                    \
    const u32 d1 = (u32)__shfl((int)w3, src1);                                    \
    PBS.u[0] = (g & 2) ? a1 : a0;                                                 \
    PBS.u[1] = (g & 2) ? b1 : b0;                                                 \
    PBS.u[2] = (g & 2) ? c1 : c0;                                                 \
    PBS.u[3] = (g & 2) ? d1 : d0;                                                 \
  }

#define ATTN_STEP(KC0, KC1, KN0, KN1)                                             \
  {                                                                               \
    const int jb = jt * 32;                                                       \
    const bool actA = (jt < sA);                                                  \
    f32x4 SB0 = (f32x4){0.f, 0.f, 0.f, 0.f}, SB1 = (f32x4){0.f, 0.f, 0.f, 0.f};   \
    f32x4 SA0 = (f32x4){0.f, 0.f, 0.f, 0.f}, SA1 = (f32x4){0.f, 0.f, 0.f, 0.f};   \
    __builtin_amdgcn_s_setprio(1);                                                \
    _Pragma("unroll")                                                             \
    for (int ks = 0; ks < 3; ++ks) {                                              \
      SB0 = MFMA16(KC0[ks], aqB[ks], SB0);                                        \
      SB1 = MFMA16(KC1[ks], aqB[ks], SB1);                                        \
    }                                                                             \
    if (actA) {                                                                   \
      _Pragma("unroll")                                                           \
      for (int ks = 0; ks < 3; ++ks) {                                            \
        SA0 = MFMA16(KC0[ks], aqA[ks], SA0);                                      \
        SA1 = MFMA16(KC1[ks], aqA[ks], SA1);                                      \
      }                                                                           \
    }                                                                             \
    __builtin_amdgcn_s_setprio(0);                                                \
    bf16x8 av[4];  /* shared V */                                                 \
    _Pragma("unroll")                                                             \
    for (int n = 0; n < 4; ++n)                                                   \
      av[n] = *(const bf16x8*)(Vh + (size_t)(n * 16 + l15) * 2048 + jb + g * 8);  \
    const int jbn = (jt + 1 < jEnd) ? jb + 32 : jb;  /* shared K prefetch */      \
    const u16* kp = Kbase + (size_t)jbn * 96;                                     \
    _Pragma("unroll")                                                             \
    for (int ks = 0; ks < 3; ++ks) {                                              \
      KN0[ks] = *(const bf16x8*)(kp + ks * 32);                                   \
      KN1[ks] = *(const bf16x8*)(kp + 16 * 96 + ks * 32);                         \
    }                                                                             \
    union { u32 u[4]; bf16x8 bv; } pbB, pbA;                                      \
    GLUE(SB0, SB1, q0B, qgB, lB, pbB);                                            \
    if (actA) GLUE(SA0, SA1, q0A, qgA, lA, pbA);                                  \
    __builtin_amdgcn_s_setprio(1);                                                \
    _Pragma("unroll")                                                             \
    for (int n = 0; n < 4; ++n) accB[n] = MFMA16(av[n], pbB.bv, accB[n]);         \
    if (actA) {                                                                   \
      _Pragma("unroll")                                                           \
      for (int n = 0; n < 4; ++n) accA[n] = MFMA16(av[n], pbA.bv, accA[n]);       \
    }                                                                             \
    __builtin_amdgcn_s_setprio(0);                                                \
  }

  int jt = jBeg;
  {
    const u16* kp0 = Kbase + (size_t)jt * 32 * 96;
#pragma unroll
    for (int ks = 0; ks < 3; ++ks) {
      kX0[ks] = *(const bf16x8*)(kp0 + ks * 32);
      kX1[ks] = *(const bf16x8*)(kp0 + 16 * 96 + ks * 32);
    }
    for (;;) {
      ATTN_STEP(kX0, kX1, kY0, kY1);
      if (++jt >= jEnd) break;
      ATTN_STEP(kY0, kY1, kX0, kX1);
      if (++jt >= jEnd) break;
    }
  }
#undef ATTN_STEP
#undef GLUE

  // epilogue: reduce row-sum partials, store unnormalized split partials
  lA += __shfl_xor(lA, 16);
  lA += __shfl_xor(lA, 32);
  lB += __shfl_xor(lB, 16);
  lB += __shfl_xor(lB, 32);
  u16* Op = split ? Op1 : Op0;
  float* lp = split ? lp1 : lp0;
  const size_t sbA = ((size_t)h * 2048 + qgA) * 64 + g * 4;
  const size_t sbB = ((size_t)h * 2048 + qgB) * 64 + g * 4;
#pragma unroll
  for (int n = 0; n < 4; ++n) {
    uint2 wa, wb;
    wa.x = pack2(accA[n][0], accA[n][1]);
    wa.y = pack2(accA[n][2], accA[n][3]);
    wb.x = pack2(accB[n][0], accB[n][1]);
    wb.y = pack2(accB[n][2], accB[n][3]);
    *(uint2*)(Op + sbA + n * 16) = wa;
    *(uint2*)(Op + sbB + n * 16) = wb;
  }
  if (lane < 16) {
    lp[(size_t)h * 2048 + qgA] = lA;
    lp[(size_t)h * 2048 + qgB] = lB;
  }
}

// ---------------- combine: AO[q][h*64+d] = (O0+O1)/(l0+l1) ----------------
__global__ __launch_bounds__(256) void k_comb(const u16* __restrict__ Op0, const u16* __restrict__ Op1,
                                              const float* __restrict__ lp0, const float* __restrict__ lp1,
                                              u16* __restrict__ AO, int nsplit) {
  const int idx = blockIdx.x * 256 + threadIdx.x;  // 262144
  const int d8 = idx & 7;
  const int hq = idx >> 3;          // h*2048 + q
  const int q = hq & 2047, h = hq >> 11;
  float l = lp0[hq];
  union { uint4 v; u16 s[8]; } a;
  a.v = *(const uint4*)(Op0 + (size_t)hq * 64 + d8 * 8);
  float o[8];
#pragma unroll
  for (int i = 0; i < 8; ++i) o[i] = b2f(a.s[i]);
  if (nsplit == 2) {
    l += lp1[hq];
    union { uint4 v; u16 s[8]; } bb;
    bb.v = *(const uint4*)(Op1 + (size_t)hq * 64 + d8 * 8);
#pragma unroll
    for (int i = 0; i < 8; ++i) o[i] += b2f(bb.s[i]);
  }
  const float inv = 1.0f / l;
  uint4 w;
  w.x = pack2(o[0] * inv, o[1] * inv);
  w.y = pack2(o[2] * inv, o[3] * inv);
  w.z = pack2(o[4] * inv, o[5] * inv);
  w.w = pack2(o[6] * inv, o[7] * inv);
  *(uint4*)(AO + (size_t)q * 1024 + h * 64 + d8 * 8) = w;
}

// ---------------- GEMM out: AO @ WoutT + bout  (M=2048, N=1024, K=1024) ----------------
__global__ __launch_bounds__(256) void k_gemm_out(const u16* __restrict__ AO, const u16* __restrict__ WoT,
                                                  const float* __restrict__ bout, float* __restrict__ out) {
  __shared__ __align__(16) u16 ldsA[128 * 64];
  __shared__ __align__(16) u16 ldsB[64 * 64];
  const int bid = blockIdx.x;                     // 256 blocks
  const int bn = bid & 15, bm = bid >> 4;
  f32x4 acc[4][2];
#pragma unroll
  for (int m = 0; m < 4; ++m)
#pragma unroll
    for (int n = 0; n < 2; ++n) acc[m][n] = (f32x4){0.f, 0.f, 0.f, 0.f};
  gemm_core_128x64(AO, WoT, bm * 128, bn * 64, 1024, ldsA, ldsB, acc);

  const int tid = threadIdx.x;
  const int wave = tid >> 6, lane = tid & 63;
  const int wr = wave >> 1, wc = wave & 1;
  const int g = lane >> 4, l15 = lane & 15;
  const int tbase = bm * 128 + wr * 64 + g * 4;
  const int cbase = bn * 64 + wc * 32 + l15;
#pragma unroll
  for (int m = 0; m < 4; ++m)
#pragma unroll
    for (int n = 0; n < 2; ++n) {
      const int c = cbase + n * 16;
      const float bb = bout[c];
#pragma unroll
      for (int r = 0; r < 4; ++r) {
        const int t = tbase + m * 16 + r;
        out[(size_t)t * 1024 + c] = acc[m][n][r] + bb;
      }
    }
}

// ---------------- launch ----------------
extern "C" void kernel_launch(void* const* d_in, const int* in_sizes, int n_in,
                              void* d_out, int out_size, void* d_ws, size_t ws_size,
                              hipStream_t stream) {
  const float* x      = (const float*)d_in[0];
  const float* Wqkv   = (const float*)d_in[1];
  const float* bqkv   = (const float*)d_in[2];
  const float* W1p    = (const float*)d_in[3];
  const float* W2p    = (const float*)d_in[4];
  const float* pscale = (const float*)d_in[5];
  const float* Wout   = (const float*)d_in[6];
  const float* bout   = (const float*)d_in[7];
  float* out = (float*)d_out;

  char* ws = (char*)d_ws;
  u16*   WB    = (u16*)(ws + 0);          // [3200][1024] bf16
  u16*   WoT   = (u16*)(ws + 6553600);    // [1024][1024] bf16
  u16*   xb    = (u16*)(ws + 8650752);    // [2048][1024] bf16 (reused as Op0 after gemm)
  u16*   Qext  = (u16*)(ws + 12845056);   // [16][2048][96] bf16 (q*0.1803 | s*log2e*L | 0)
  u16*   Kext  = (u16*)(ws + 19136512);   // [16][2048][96] bf16 (k | J·L | 0)
  u16*   Vt    = (u16*)(ws + 25427968);   // [16][64][2048] bf16
  float* P12   = (float*)(ws + 29622272); // [2048][128] f32 (reused as lp0 after k_lines)
  u16*   AO    = (u16*)(ws + 30670848);   // [2048][1024] bf16

  u16*   Op0   = xb;                      // [16][2048][64] bf16 unnormalized O, split 0
  float* lp0   = P12;                     // [16][2048] f32
  u16*   Op1   = (u16*)(ws + 34865152);   // split 1
  float* lp1   = (float*)(ws + 39059456);
  const int nsplit = (ws_size >= 39190528ull) ? 2 : 1;
  if (nsplit == 1) { Op1 = Op0; lp1 = lp0; }

  k_prep<<<6656, 256, 0, stream>>>(Wqkv, Wout, W1p, W2p, x, WB, WoT, xb);
  k_gemm_qkvp<<<800, 256, 0, stream>>>(xb, WB, bqkv, Qext, Kext, Vt, P12);
  k_lines<<<128, 256, 0, stream>>>(P12, pscale, Qext, Kext);
  k_attn<<<1024 * nsplit, 64, 0, stream>>>(Qext, Kext, Vt, Op0, Op1, lp0, lp1, nsplit);
  k_comb<<<1024, 256, 0, stream>>>(Op0, Op1, lp0, lp1, AO, nsplit);
  k_gemm_out<<<256, 256, 0, stream>>>(AO, WoT, bout, out);
}

// Round 8
// 113.107 us; speedup vs baseline: 1.0422x; 1.0422x over previous
//
#include <hip/hip_runtime.h>

typedef unsigned short u16;
typedef unsigned int u32;
typedef __attribute__((ext_vector_type(8))) __bf16 bf16x8;
typedef __attribute__((ext_vector_type(4))) float f32x4;
typedef __attribute__((ext_vector_type(4))) u16 u16x4;

#define MFMA16(a, b, c) __builtin_amdgcn_mfma_f32_16x16x32_bf16((a), (b), (c), 0, 0, 0)

static __device__ __forceinline__ u16 f2b(float f) {
  union { float f; u32 u; } v; v.f = f;
  u32 u = v.u;
  return (u16)((u + 0x7FFFu + ((u >> 16) & 1u)) >> 16);
}

// packed f32x2 -> bf16x2 (RNE), low half = a
static __device__ __forceinline__ u32 pack2(float a, float b) {
  u32 r;
  asm("v_cvt_pk_bf16_f32 %0, %1, %2" : "=v"(r) : "v"(a), "v"(b));
  return r;
}

static __device__ __forceinline__ float exp2fast(float x) {
#if defined(__has_builtin) && __has_builtin(__builtin_amdgcn_exp2f)
  return __builtin_amdgcn_exp2f(x);
#else
  return __expf(x * 0.6931471805599453f);
#endif
}

static __device__ __forceinline__ void gload16(const u16* gp, u16* lp) {
  __builtin_amdgcn_global_load_lds((__attribute__((address_space(1))) void*)(u16*)gp,
                                   (__attribute__((address_space(3))) void*)lp, 16, 0, 0);
}

// ---------------- merged prep kernel ----------------
__global__ __launch_bounds__(256) void k_prep(const float* __restrict__ Wqkv, const float* __restrict__ Wout,
                                              const float* __restrict__ W1p, const float* __restrict__ W2p,
                                              const float* __restrict__ x,
                                              u16* __restrict__ WB, u16* __restrict__ WoT,
                                              u16* __restrict__ xb) {
  const int b = blockIdx.x;
  const int t = threadIdx.x;
  if (b < 4096) {
    __shared__ float tile[32][33];
    const float* src; u16* dst; int N, n0, k0;
    if (b < 3072) { src = Wqkv; dst = WB;  N = 3072; n0 = (b % 96) * 32; k0 = (b / 96) * 32; }
    else { const int bb = b - 3072; src = Wout; dst = WoT; N = 1024; n0 = (bb & 31) * 32; k0 = (bb >> 5) * 32; }
    const int r = t >> 3, c4 = (t & 7) << 2;
    const float4 in4 = *(const float4*)(src + (size_t)(k0 + r) * N + n0 + c4);
    tile[r][c4 + 0] = in4.x; tile[r][c4 + 1] = in4.y;
    tile[r][c4 + 2] = in4.z; tile[r][c4 + 3] = in4.w;
    __syncthreads();
    u16x4 o;
    o.x = f2b(tile[c4 + 0][r]); o.y = f2b(tile[c4 + 1][r]);
    o.z = f2b(tile[c4 + 2][r]); o.w = f2b(tile[c4 + 3][r]);
    *(u16x4*)(dst + (size_t)(n0 + r) * 1024 + k0 + c4) = o;
  } else if (b < 4608) {
    const int idx = (b - 4096) * 256 + t;  // 131072
    const int j = idx >> 10, k = idx & 1023;
    const float v = (j < 64) ? W1p[(size_t)k * 64 + j] : W2p[(size_t)k * 64 + (j - 64)];
    WB[(size_t)3072 * 1024 + idx] = f2b(v);
  } else {
    const size_t idx = ((size_t)(b - 4608) * 256 + t) << 2;
    const float4 v = *(const float4*)(x + idx);
    u16x4 o; o.x = f2b(v.x); o.y = f2b(v.y); o.z = f2b(v.z); o.w = f2b(v.w);
    *(u16x4*)(xb + idx) = o;
  }
}

// ---------------- 128x128 bf16 MFMA GEMM core (BK=64, global_load_lds, XOR swizzle) ----------------
static __device__ __forceinline__ void gemm128_core(const u16* __restrict__ A, const u16* __restrict__ B,
                                                    int brow, int bcol, int K,
                                                    u16* ldsA, u16* ldsB, f32x4 acc[4][4]) {
  const int tid = threadIdx.x;
  const int wave = tid >> 6, lane = tid & 63;
  const int wr = wave >> 1, wc = wave & 1;
  const int g = lane >> 4, l15 = lane & 15;

  for (int k0 = 0; k0 < K; k0 += 64) {
#pragma unroll
    for (int li = 0; li < 4; ++li) {
      const int f = li * 256 + wave * 64 + lane;   // 16B chunk index in [0,1024)
      const int row = f >> 3;
      const int slot = f & 7;
      const int gcol = ((slot ^ (row & 7)) << 3);  // pre-swizzled global source col
      const u16* ga = A + (size_t)(brow + row) * K + k0 + gcol;
      const u16* gb = B + (size_t)(bcol + row) * K + k0 + gcol;
      u16* la = ldsA + (size_t)(li * 256 + wave * 64) * 8;  // wave-uniform base
      u16* lb = ldsB + (size_t)(li * 256 + wave * 64) * 8;
      gload16(ga, la);
      gload16(gb, lb);
    }
    __syncthreads();
    bf16x8 af[4][2], bfr[4][2];
#pragma unroll
    for (int m = 0; m < 4; ++m) {
#pragma unroll
      for (int kk = 0; kk < 2; ++kk) {
        const int rowA = wr * 64 + m * 16 + l15;
        const int chA = (kk * 4 + g) ^ (rowA & 7);
        af[m][kk] = *(const bf16x8*)(ldsA + (size_t)rowA * 64 + chA * 8);
        const int rowB = wc * 64 + m * 16 + l15;
        const int chB = (kk * 4 + g) ^ (rowB & 7);
        bfr[m][kk] = *(const bf16x8*)(ldsB + (size_t)rowB * 64 + chB * 8);
      }
    }
#pragma unroll
    for (int m = 0; m < 4; ++m)
#pragma unroll
      for (int n = 0; n < 4; ++n)
#pragma unroll
        for (int kk = 0; kk < 2; ++kk)
          acc[m][n] = MFMA16(af[m][kk], bfr[n][kk], acc[m][n]);
    __syncthreads();
  }
}

// ---------------- 128x64 bf16 MFMA GEMM core (for gemm_out) ----------------
static __device__ __forceinline__ void gemm_core_128x64(const u16* __restrict__ A, const u16* __restrict__ B,
                                                        int brow, int bcol, int K,
                                                        u16* ldsA, u16* ldsB, f32x4 acc[4][2]) {
  const int tid = threadIdx.x;
  const int wave = tid >> 6, lane = tid & 63;
  const int wr = wave >> 1, wc = wave & 1;
  const int g = lane >> 4, l15 = lane & 15;

  for (int k0 = 0; k0 < K; k0 += 64) {
#pragma unroll
    for (int li = 0; li < 4; ++li) {
      const int f = li * 256 + wave * 64 + lane;
      const int row = f >> 3;
      const int slot = f & 7;
      const int gcol = ((slot ^ (row & 7)) << 3);
      gload16(A + (size_t)(brow + row) * K + k0 + gcol, ldsA + (size_t)(li * 256 + wave * 64) * 8);
    }
#pragma unroll
    for (int li = 0; li < 2; ++li) {
      const int f = li * 256 + wave * 64 + lane;
      const int row = f >> 3;
      const int slot = f & 7;
      const int gcol = ((slot ^ (row & 7)) << 3);
      gload16(B + (size_t)(bcol + row) * K + k0 + gcol, ldsB + (size_t)(li * 256 + wave * 64) * 8);
    }
    __syncthreads();
    bf16x8 af[4][2], bfr[2][2];
#pragma unroll
    for (int kk = 0; kk < 2; ++kk) {
#pragma unroll
      for (int m = 0; m < 4; ++m) {
        const int rowA = wr * 64 + m * 16 + l15;
        const int chA = (kk * 4 + g) ^ (rowA & 7);
        af[m][kk] = *(const bf16x8*)(ldsA + (size_t)rowA * 64 + chA * 8);
      }
#pragma unroll
      for (int n = 0; n < 2; ++n) {
        const int rowB = wc * 32 + n * 16 + l15;
        const int chB = (kk * 4 + g) ^ (rowB & 7);
        bfr[n][kk] = *(const bf16x8*)(ldsB + (size_t)rowB * 64 + chB * 8);
      }
    }
#pragma unroll
    for (int m = 0; m < 4; ++m)
#pragma unroll
      for (int n = 0; n < 2; ++n)
#pragma unroll
        for (int kk = 0; kk < 2; ++kk)
          acc[m][n] = MFMA16(af[m][kk], bfr[n][kk], acc[m][n]);
    __syncthreads();
  }
}

// ---------------- GEMM1: x @ [Wqkv|W1p|W2p]  (M=2048, N=3200, K=1024), 128x128 tile ----------------
// Q prescale = 0.125 * log2(e); V stored TILED: Vt[h][jt][d][tin] = [h][64][64][32]
__global__ __launch_bounds__(256) void k_gemm_qkvp(const u16* __restrict__ xb, const u16* __restrict__ WB,
                                                   const float* __restrict__ bqkv,
                                                   u16* __restrict__ Qext, u16* __restrict__ Kext,
                                                   u16* __restrict__ Vt, float* __restrict__ P12) {
  __shared__ __align__(16) u16 ldsA[128 * 64];
  __shared__ __align__(16) u16 ldsB[128 * 64];
  const int bid = blockIdx.x;                      // 400 blocks
  const int bn = bid % 25, bm = bid / 25;
  f32x4 acc[4][4];
#pragma unroll
  for (int m = 0; m < 4; ++m)
#pragma unroll
    for (int n = 0; n < 4; ++n) acc[m][n] = (f32x4){0.f, 0.f, 0.f, 0.f};
  gemm128_core(xb, WB, bm * 128, bn * 128, 1024, ldsA, ldsB, acc);

  const int tid = threadIdx.x;
  const int wave = tid >> 6, lane = tid & 63;
  const int wr = wave >> 1, wc = wave & 1;
  const int g = lane >> 4, l15 = lane & 15;
  const int tbase = bm * 128 + wr * 64 + g * 4;
  const int cbase = bn * 128 + wc * 64 + l15;
#pragma unroll
  for (int m = 0; m < 4; ++m) {
#pragma unroll
    for (int n = 0; n < 4; ++n) {
      const int c = cbase + n * 16;
#pragma unroll
      for (int r = 0; r < 4; ++r) {
        const int t = tbase + m * 16 + r;
        float v = acc[m][n][r];
        if (c < 3072) {
          v += bqkv[c];
          const int sub = c >> 10;
          const int rem = c & 1023;
          const int hh = rem >> 6, d = rem & 63;
          if (sub == 0)      Qext[((size_t)hh * 2048 + t) * 96 + d] = f2b(v * 0.18033688f);
          else if (sub == 1) Kext[((size_t)hh * 2048 + t) * 96 + d] = f2b(v);
          else               Vt[(size_t)hh * 131072 + (size_t)(t >> 5) * 2048 + d * 32 + (t & 31)] = f2b(v);
        } else {
          P12[(size_t)t * 128 + (c - 3072)] = v;
        }
      }
    }
  }
}

// ---------------- Plucker lines -> Qext/Kext cols 64..95 ----------------
__global__ __launch_bounds__(256) void k_lines(const float* __restrict__ P12, const float* __restrict__ pscale,
                                               u16* __restrict__ Qext, u16* __restrict__ Kext) {
  const int idx = blockIdx.x * 256 + threadIdx.x;  // 32768 = 2048*16
  const int t = idx >> 4, h = idx & 15;
  const float* p = P12 + (size_t)t * 128;
  const float a0 = p[h * 4 + 0], a1 = p[h * 4 + 1], a2 = p[h * 4 + 2], a3 = p[h * 4 + 3];
  const float b0 = p[64 + h * 4 + 0], b1 = p[64 + h * 4 + 1], b2 = p[64 + h * 4 + 2], b3 = p[64 + h * 4 + 3];
  float L0 = a0 * b1 - a1 * b0;
  float L1 = a0 * b2 - a2 * b0;
  float L2 = a0 * b3 - a3 * b0;
  float L3 = a1 * b2 - a2 * b1;
  float L4 = a1 * b3 - a3 * b1;
  float L5 = a2 * b3 - a3 * b2;
  const float nrm = sqrtf(L0 * L0 + L1 * L1 + L2 * L2 + L3 * L3 + L4 * L4 + L5 * L5);
  const float inv = 1.0f / fmaxf(nrm, 1e-12f);
  L0 *= inv; L1 *= inv; L2 *= inv; L3 *= inv; L4 *= inv; L5 *= inv;
  const float s = pscale[h] * 1.44269504f;  // fold log2(e) into q-side bias
  u16* q = Qext + ((size_t)h * 2048 + t) * 96 + 64;
  u16* k = Kext + ((size_t)h * 2048 + t) * 96 + 64;
  q[0] = f2b(L0 * s); q[1] = f2b(L1 * s); q[2] = f2b(L2 * s);
  q[3] = f2b(L3 * s); q[4] = f2b(L4 * s); q[5] = f2b(L5 * s);
  // Jlines = J6 @ L : [L5, -L4, L3, L2, -L1, L0]
  k[0] = f2b(L5); k[1] = f2b(-L4); k[2] = f2b(L3);
  k[3] = f2b(L2); k[4] = f2b(-L1); k[5] = f2b(L0);
#pragma unroll
  for (int c = 6; c < 32; ++c) { q[c] = 0; k[c] = 0; }
}

// ---------------- fused causal attention: paired-tile dual-stream waves (R6) ----------------
// ONE change vs R6: V read from TILED layout [h][jt][64][32] (4KB contiguous per KV step).
__global__ __launch_bounds__(64) void k_attn(const u16* __restrict__ Qext, const u16* __restrict__ Kext,
                                             const u16* __restrict__ Vt, u16* __restrict__ AO) {
  const int bid = blockIdx.x;                     // 1024 blocks = 16 heads x 64 pairs
  const int h = bid & 15;
  const int p = bid >> 4;                         // 0..63
  const int lane = threadIdx.x;
  const int g = lane >> 4, l15 = lane & 15;
  const int q0A = p << 4;
  const int q0B = (127 - p) << 4;
  const int qgA = q0A + l15;
  const int qgB = q0B + l15;
  const int sA = (p >> 1) + 1;                    // steps for tile A
  const int sB = ((127 - p) >> 1) + 1;            // steps for tile B (>= sA)
  const u16* Qh = Qext + (size_t)h * 2048 * 96;
  const u16* Kh = Kext + (size_t)h * 2048 * 96;
  const u16* Vh = Vt + (size_t)h * 131072;

  bf16x8 aqA[3], aqB[3];
#pragma unroll
  for (int ks = 0; ks < 3; ++ks) {
    aqA[ks] = *(const bf16x8*)(Qh + (size_t)qgA * 96 + ks * 32 + g * 8);
    aqB[ks] = *(const bf16x8*)(Qh + (size_t)qgB * 96 + ks * 32 + g * 8);
  }

  f32x4 accA[4], accB[4];
#pragma unroll
  for (int n = 0; n < 4; ++n) {
    accA[n] = (f32x4){0.f, 0.f, 0.f, 0.f};
    accB[n] = (f32x4){0.f, 0.f, 0.f, 0.f};
  }
  float lA = 0.f, lB = 0.f;

  const u16* Kbase = Kh + (size_t)l15 * 96 + g * 8;
  const int src0 = ((g & 1) << 5) + l15;
  const int src1 = src0 + 16;

  bf16x8 kX0[3], kX1[3], kY0[3], kY1[3];
#pragma unroll
  for (int ks = 0; ks < 3; ++ks) {
    kX0[ks] = *(const bf16x8*)(Kbase + ks * 32);
    kX1[ks] = *(const bf16x8*)(Kbase + 16 * 96 + ks * 32);
  }

#define GLUE(S0, S1, Q0S, QGS, LS, PBS)                                           \
  {                                                                               \
    if (jb + 31 > Q0S) {                                                          \
      _Pragma("unroll")                                                           \
      for (int r = 0; r < 4; ++r) {                                               \
        if (jb + g * 4 + r > QGS) S0[r] = -1e30f;                                 \
        if (jb + 16 + g * 4 + r > QGS) S1[r] = -1e30f;                            \
      }                                                                           \
    }                                                                             \
    _Pragma("unroll")                                                             \
    for (int r = 0; r < 4; ++r) {                                                 \
      S0[r] = exp2fast(S0[r]);                                                    \
      S1[r] = exp2fast(S1[r]);                                                    \
    }                                                                             \
    LS += ((S0[0] + S0[1]) + (S0[2] + S0[3])) + ((S1[0] + S1[1]) + (S1[2] + S1[3])); \
    const u32 w0 = pack2(S0[0], S0[1]);                                           \
    const u32 w1 = pack2(S0[2], S0[3]);                                           \
    const u32 w2 = pack2(S1[0], S1[1]);                                           \
    const u32 w3 = pack2(S1[2], S1[3]);                                           \
    const u32 a0 = (u32)__shfl((int)w0, src0);                                    \
    const u32 a1 = (u32)__shfl((int)w2, src0);                                    \
    const u32 b0 = (u32)__shfl((int)w1, src0);                                    \
    const u32 b1 = (u32)__shfl((int)w3, src0);                                    \
    const u32 c0 = (u32)__shfl((int)w0, src1);                                    \
    const u32 c1 = (u32)__shfl((int)w2, src1);                                    \
    const u32 d0 = (u32)__shfl((int)w1, src1);                                    \
    const u32 d1 = (u32)__shfl((int)w3, src1);                                    \
    PBS.u[0] = (g & 2) ? a1 : a0;                                                 \
    PBS.u[1] = (g & 2) ? b1 : b0;                                                 \
    PBS.u[2] = (g & 2) ? c1 : c0;                                                 \
    PBS.u[3] = (g & 2) ? d1 : d0;                                                 \
  }

#define ATTN_STEP(KC0, KC1, KN0, KN1)                                             \
  {                                                                               \
    const int jb = jt * 32;                                                       \
    const bool actA = (jt < sA);                                                  \
    f32x4 SB0 = (f32x4){0.f, 0.f, 0.f, 0.f}, SB1 = (f32x4){0.f, 0.f, 0.f, 0.f};   \
    f32x4 SA0 = (f32x4){0.f, 0.f, 0.f, 0.f}, SA1 = (f32x4){0.f, 0.f, 0.f, 0.f};   \
    __builtin_amdgcn_s_setprio(1);                                                \
    _Pragma("unroll")                                                             \
    for (int ks = 0; ks < 3; ++ks) {                                              \
      SB0 = MFMA16(KC0[ks], aqB[ks], SB0);                                        \
      SB1 = MFMA16(KC1[ks], aqB[ks], SB1);                                        \
    }                                                                             \
    if (actA) {                                                                   \
      _Pragma("unroll")                                                           \
      for (int ks = 0; ks < 3; ++ks) {                                            \
        SA0 = MFMA16(KC0[ks], aqA[ks], SA0);                                      \
        SA1 = MFMA16(KC1[ks], aqA[ks], SA1);                                      \
      }                                                                           \
    }                                                                             \
    __builtin_amdgcn_s_setprio(0);                                                \
    bf16x8 av[4];  /* shared V from tiled layout: 4KB contiguous tile */          \
    _Pragma("unroll")                                                             \
    for (int n = 0; n < 4; ++n)                                                   \
      av[n] = *(const bf16x8*)(Vh + (size_t)jb * 64 + (n * 16 + l15) * 32 + g * 8); \
    const int jbn = (jt + 1 < sB) ? jb + 32 : jb;  /* shared K prefetch */        \
    const u16* kp = Kbase + (size_t)jbn * 96;                                     \
    _Pragma("unroll")                                                             \
    for (int ks = 0; ks < 3; ++ks) {                                              \
      KN0[ks] = *(const bf16x8*)(kp + ks * 32);                                   \
      KN1[ks] = *(const bf16x8*)(kp + 16 * 96 + ks * 32);                         \
    }                                                                             \
    union { u32 u[4]; bf16x8 bv; } pbB, pbA;                                      \
    GLUE(SB0, SB1, q0B, qgB, lB, pbB);                                            \
    if (actA) GLUE(SA0, SA1, q0A, qgA, lA, pbA);                                  \
    __builtin_amdgcn_s_setprio(1);                                                \
    _Pragma("unroll")                                                             \
    for (int n = 0; n < 4; ++n) accB[n] = MFMA16(av[n], pbB.bv, accB[n]);         \
    if (actA) {                                                                   \
      _Pragma("unroll")                                                           \
      for (int n = 0; n < 4; ++n) accA[n] = MFMA16(av[n], pbA.bv, accA[n]);       \
    }                                                                             \
    __builtin_amdgcn_s_setprio(0);                                                \
  }

  int jt = 0;
  for (;;) {
    ATTN_STEP(kX0, kX1, kY0, kY1);
    if (++jt >= sB) break;
    ATTN_STEP(kY0, kY1, kX0, kX1);
    if (++jt >= sB) break;
  }
#undef ATTN_STEP
#undef GLUE

  // epilogue: reduce row-sum partials across the 4 g-groups, normalize, store (both streams)
  lA += __shfl_xor(lA, 16);
  lA += __shfl_xor(lA, 32);
  lB += __shfl_xor(lB, 16);
  lB += __shfl_xor(lB, 32);
  const float invA = 1.0f / lA;
  const float invB = 1.0f / lB;
  u32* dstA = (u32*)(AO + (size_t)qgA * 1024 + h * 64 + g * 4);
  u32* dstB = (u32*)(AO + (size_t)qgB * 1024 + h * 64 + g * 4);
#pragma unroll
  for (int n = 0; n < 4; ++n) {
    dstA[n * 8 + 0] = pack2(accA[n][0] * invA, accA[n][1] * invA);
    dstA[n * 8 + 1] = pack2(accA[n][2] * invA, accA[n][3] * invA);
    dstB[n * 8 + 0] = pack2(accB[n][0] * invB, accB[n][1] * invB);
    dstB[n * 8 + 1] = pack2(accB[n][2] * invB, accB[n][3] * invB);
  }
}

// ---------------- GEMM out: AO @ WoutT + bout  (M=2048, N=1024, K=1024) ----------------
__global__ __launch_bounds__(256) void k_gemm_out(const u16* __restrict__ AO, const u16* __restrict__ WoT,
                                                  const float* __restrict__ bout, float* __restrict__ out) {
  __shared__ __align__(16) u16 ldsA[128 * 64];
  __shared__ __align__(16) u16 ldsB[64 * 64];
  const int bid = blockIdx.x;                     // 256 blocks
  const int bn = bid & 15, bm = bid >> 4;
  f32x4 acc[4][2];
#pragma unroll
  for (int m = 0; m < 4; ++m)
#pragma unroll
    for (int n = 0; n < 2; ++n) acc[m][n] = (f32x4){0.f, 0.f, 0.f, 0.f};
  gemm_core_128x64(AO, WoT, bm * 128, bn * 64, 1024, ldsA, ldsB, acc);

  const int tid = threadIdx.x;
  const int wave = tid >> 6, lane = tid & 63;
  const int wr = wave >> 1, wc = wave & 1;
  const int g = lane >> 4, l15 = lane & 15;
  const int tbase = bm * 128 + wr * 64 + g * 4;
  const int cbase = bn * 64 + wc * 32 + l15;
#pragma unroll
  for (int m = 0; m < 4; ++m)
#pragma unroll
    for (int n = 0; n < 2; ++n) {
      const int c = cbase + n * 16;
      const float bb = bout[c];
#pragma unroll
      for (int r = 0; r < 4; ++r) {
        const int t = tbase + m * 16 + r;
        out[(size_t)t * 1024 + c] = acc[m][n][r] + bb;
      }
    }
}

// ---------------- launch ----------------
extern "C" void kernel_launch(void* const* d_in, const int* in_sizes, int n_in,
                              void* d_out, int out_size, void* d_ws, size_t ws_size,
                              hipStream_t stream) {
  const float* x      = (const float*)d_in[0];
  const float* Wqkv   = (const float*)d_in[1];
  const float* bqkv   = (const float*)d_in[2];
  const float* W1p    = (const float*)d_in[3];
  const float* W2p    = (const float*)d_in[4];
  const float* pscale = (const float*)d_in[5];
  const float* Wout   = (const float*)d_in[6];
  const float* bout   = (const float*)d_in[7];
  float* out = (float*)d_out;

  char* ws = (char*)d_ws;
  u16*   WB    = (u16*)(ws + 0);          // [3200][1024] bf16
  u16*   WoT   = (u16*)(ws + 6553600);    // [1024][1024] bf16
  u16*   xb    = (u16*)(ws + 8650752);    // [2048][1024] bf16
  u16*   Qext  = (u16*)(ws + 12845056);   // [16][2048][96] bf16 (q*0.1803 | s*log2e*L | 0)
  u16*   Kext  = (u16*)(ws + 19136512);   // [16][2048][96] bf16 (k | J·L | 0)
  u16*   Vt    = (u16*)(ws + 25427968);   // [16][64][64][32] bf16 (tiled V^T)
  float* P12   = (float*)(ws + 29622272); // [2048][128] f32
  u16*   AO    = (u16*)(ws + 30670848);   // [2048][1024] bf16

  k_prep<<<6656, 256, 0, stream>>>(Wqkv, Wout, W1p, W2p, x, WB, WoT, xb);
  k_gemm_qkvp<<<400, 256, 0, stream>>>(xb, WB, bqkv, Qext, Kext, Vt, P12);
  k_lines<<<128, 256, 0, stream>>>(P12, pscale, Qext, Kext);
  k_attn<<<1024, 64, 0, stream>>>(Qext, Kext, Vt, AO);
  k_gemm_out<<<256, 256, 0, stream>>>(AO, WoT, bout, out);
}

// Round 9
// 102.033 us; speedup vs baseline: 1.1553x; 1.1085x over previous
//
#include <hip/hip_runtime.h>

typedef unsigned short u16;
typedef unsigned int u32;
typedef __attribute__((ext_vector_type(8))) __bf16 bf16x8;
typedef __attribute__((ext_vector_type(4))) float f32x4;
typedef __attribute__((ext_vector_type(4))) u16 u16x4;

#define MFMA16(a, b, c) __builtin_amdgcn_mfma_f32_16x16x32_bf16((a), (b), (c), 0, 0, 0)

static __device__ __forceinline__ u16 f2b(float f) {
  union { float f; u32 u; } v; v.f = f;
  u32 u = v.u;
  return (u16)((u + 0x7FFFu + ((u >> 16) & 1u)) >> 16);
}

// packed f32x2 -> bf16x2 (RNE), low half = a
static __device__ __forceinline__ u32 pack2(float a, float b) {
  u32 r;
  asm("v_cvt_pk_bf16_f32 %0, %1, %2" : "=v"(r) : "v"(a), "v"(b));
  return r;
}

static __device__ __forceinline__ float exp2fast(float x) {
#if defined(__has_builtin) && __has_builtin(__builtin_amdgcn_exp2f)
  return __builtin_amdgcn_exp2f(x);
#else
  return __expf(x * 0.6931471805599453f);
#endif
}

static __device__ __forceinline__ void gload16(const u16* gp, u16* lp) {
  __builtin_amdgcn_global_load_lds((__attribute__((address_space(1))) void*)(u16*)gp,
                                   (__attribute__((address_space(3))) void*)lp, 16, 0, 0);
}

// ---------------- merged prep kernel ----------------
__global__ __launch_bounds__(256) void k_prep(const float* __restrict__ Wqkv, const float* __restrict__ Wout,
                                              const float* __restrict__ W1p, const float* __restrict__ W2p,
                                              const float* __restrict__ x,
                                              u16* __restrict__ WB, u16* __restrict__ WoT,
                                              u16* __restrict__ xb) {
  const int b = blockIdx.x;
  const int t = threadIdx.x;
  if (b < 4096) {
    __shared__ float tile[32][33];
    const float* src; u16* dst; int N, n0, k0;
    if (b < 3072) { src = Wqkv; dst = WB;  N = 3072; n0 = (b % 96) * 32; k0 = (b / 96) * 32; }
    else { const int bb = b - 3072; src = Wout; dst = WoT; N = 1024; n0 = (bb & 31) * 32; k0 = (bb >> 5) * 32; }
    const int r = t >> 3, c4 = (t & 7) << 2;
    const float4 in4 = *(const float4*)(src + (size_t)(k0 + r) * N + n0 + c4);
    tile[r][c4 + 0] = in4.x; tile[r][c4 + 1] = in4.y;
    tile[r][c4 + 2] = in4.z; tile[r][c4 + 3] = in4.w;
    __syncthreads();
    u16x4 o;
    o.x = f2b(tile[c4 + 0][r]); o.y = f2b(tile[c4 + 1][r]);
    o.z = f2b(tile[c4 + 2][r]); o.w = f2b(tile[c4 + 3][r]);
    *(u16x4*)(dst + (size_t)(n0 + r) * 1024 + k0 + c4) = o;
  } else if (b < 4608) {
    const int idx = (b - 4096) * 256 + t;  // 131072
    const int j = idx >> 10, k = idx & 1023;
    const float v = (j < 64) ? W1p[(size_t)k * 64 + j] : W2p[(size_t)k * 64 + (j - 64)];
    WB[(size_t)3072 * 1024 + idx] = f2b(v);
  } else {
    const size_t idx = ((size_t)(b - 4608) * 256 + t) << 2;
    const float4 v = *(const float4*)(x + idx);
    u16x4 o; o.x = f2b(v.x); o.y = f2b(v.y); o.z = f2b(v.z); o.w = f2b(v.w);
    *(u16x4*)(xb + idx) = o;
  }
}

// ---------------- 128x64 bf16 MFMA GEMM core (BK=64, global_load_lds, XOR swizzle) ----------------
static __device__ __forceinline__ void gemm_core_128x64(const u16* __restrict__ A, const u16* __restrict__ B,
                                                        int brow, int bcol, int K,
                                                        u16* ldsA, u16* ldsB, f32x4 acc[4][2]) {
  const int tid = threadIdx.x;
  const int wave = tid >> 6, lane = tid & 63;
  const int wr = wave >> 1, wc = wave & 1;
  const int g = lane >> 4, l15 = lane & 15;

  for (int k0 = 0; k0 < K; k0 += 64) {
#pragma unroll
    for (int li = 0; li < 4; ++li) {
      const int f = li * 256 + wave * 64 + lane;
      const int row = f >> 3;
      const int slot = f & 7;
      const int gcol = ((slot ^ (row & 7)) << 3);
      gload16(A + (size_t)(brow + row) * K + k0 + gcol, ldsA + (size_t)(li * 256 + wave * 64) * 8);
    }
#pragma unroll
    for (int li = 0; li < 2; ++li) {
      const int f = li * 256 + wave * 64 + lane;
      const int row = f >> 3;
      const int slot = f & 7;
      const int gcol = ((slot ^ (row & 7)) << 3);
      gload16(B + (size_t)(bcol + row) * K + k0 + gcol, ldsB + (size_t)(li * 256 + wave * 64) * 8);
    }
    __syncthreads();
    bf16x8 af[4][2], bfr[2][2];
#pragma unroll
    for (int kk = 0; kk < 2; ++kk) {
#pragma unroll
      for (int m = 0; m < 4; ++m) {
        const int rowA = wr * 64 + m * 16 + l15;
        const int chA = (kk * 4 + g) ^ (rowA & 7);
        af[m][kk] = *(const bf16x8*)(ldsA + (size_t)rowA * 64 + chA * 8);
      }
#pragma unroll
      for (int n = 0; n < 2; ++n) {
        const int rowB = wc * 32 + n * 16 + l15;
        const int chB = (kk * 4 + g) ^ (rowB & 7);
        bfr[n][kk] = *(const bf16x8*)(ldsB + (size_t)rowB * 64 + chB * 8);
      }
    }
#pragma unroll
    for (int m = 0; m < 4; ++m)
#pragma unroll
      for (int n = 0; n < 2; ++n)
#pragma unroll
        for (int kk = 0; kk < 2; ++kk)
          acc[m][n] = MFMA16(af[m][kk], bfr[n][kk], acc[m][n]);
    __syncthreads();
  }
}

// ---------------- GEMM1: x @ [Wqkv|W1p|W2p]  (M=2048, N=3200, K=1024), 128x64 tile ----------------
// Q prescale = 0.125 * log2(e); V stored TILED: Vt[h][jt][d][tin] = [h][64][64][32]
__global__ __launch_bounds__(256) void k_gemm_qkvp(const u16* __restrict__ xb, const u16* __restrict__ WB,
                                                   const float* __restrict__ bqkv,
                                                   u16* __restrict__ Qext, u16* __restrict__ Kext,
                                                   u16* __restrict__ Vt, float* __restrict__ P12) {
  __shared__ __align__(16) u16 ldsA[128 * 64];
  __shared__ __align__(16) u16 ldsB[64 * 64];
  const int bid = blockIdx.x;                      // 800 blocks
  const int bn = bid % 50, bm = bid / 50;
  f32x4 acc[4][2];
#pragma unroll
  for (int m = 0; m < 4; ++m)
#pragma unroll
    for (int n = 0; n < 2; ++n) acc[m][n] = (f32x4){0.f, 0.f, 0.f, 0.f};
  gemm_core_128x64(xb, WB, bm * 128, bn * 64, 1024, ldsA, ldsB, acc);

  const int tid = threadIdx.x;
  const int wave = tid >> 6, lane = tid & 63;
  const int wr = wave >> 1, wc = wave & 1;
  const int g = lane >> 4, l15 = lane & 15;
  const int tbase = bm * 128 + wr * 64 + g * 4;
  const int cbase = bn * 64 + wc * 32 + l15;
#pragma unroll
  for (int m = 0; m < 4; ++m) {
#pragma unroll
    for (int n = 0; n < 2; ++n) {
      const int c = cbase + n * 16;
#pragma unroll
      for (int r = 0; r < 4; ++r) {
        const int t = tbase + m * 16 + r;
        float v = acc[m][n][r];
        if (c < 3072) {
          v += bqkv[c];
          const int sub = c >> 10;
          const int rem = c & 1023;
          const int hh = rem >> 6, d = rem & 63;
          if (sub == 0)      Qext[((size_t)hh * 2048 + t) * 96 + d] = f2b(v * 0.18033688f);
          else if (sub == 1) Kext[((size_t)hh * 2048 + t) * 96 + d] = f2b(v);
          else               Vt[(size_t)hh * 131072 + (size_t)(t >> 5) * 2048 + d * 32 + (t & 31)] = f2b(v);
        } else {
          P12[(size_t)t * 128 + (c - 3072)] = v;
        }
      }
    }
  }
}

// ---------------- Plucker lines -> Qext/Kext cols 64..95 ----------------
__global__ __launch_bounds__(256) void k_lines(const float* __restrict__ P12, const float* __restrict__ pscale,
                                               u16* __restrict__ Qext, u16* __restrict__ Kext) {
  const int idx = blockIdx.x * 256 + threadIdx.x;  // 32768 = 2048*16
  const int t = idx >> 4, h = idx & 15;
  const float* p = P12 + (size_t)t * 128;
  const float a0 = p[h * 4 + 0], a1 = p[h * 4 + 1], a2 = p[h * 4 + 2], a3 = p[h * 4 + 3];
  const float b0 = p[64 + h * 4 + 0], b1 = p[64 + h * 4 + 1], b2 = p[64 + h * 4 + 2], b3 = p[64 + h * 4 + 3];
  float L0 = a0 * b1 - a1 * b0;
  float L1 = a0 * b2 - a2 * b0;
  float L2 = a0 * b3 - a3 * b0;
  float L3 = a1 * b2 - a2 * b1;
  float L4 = a1 * b3 - a3 * b1;
  float L5 = a2 * b3 - a3 * b2;
  const float nrm = sqrtf(L0 * L0 + L1 * L1 + L2 * L2 + L3 * L3 + L4 * L4 + L5 * L5);
  const float inv = 1.0f / fmaxf(nrm, 1e-12f);
  L0 *= inv; L1 *= inv; L2 *= inv; L3 *= inv; L4 *= inv; L5 *= inv;
  const float s = pscale[h] * 1.44269504f;  // fold log2(e) into q-side bias
  u16* q = Qext + ((size_t)h * 2048 + t) * 96 + 64;
  u16* k = Kext + ((size_t)h * 2048 + t) * 96 + 64;
  q[0] = f2b(L0 * s); q[1] = f2b(L1 * s); q[2] = f2b(L2 * s);
  q[3] = f2b(L3 * s); q[4] = f2b(L4 * s); q[5] = f2b(L5 * s);
  // Jlines = J6 @ L : [L5, -L4, L3, L2, -L1, L0]
  k[0] = f2b(L5); k[1] = f2b(-L4); k[2] = f2b(L3);
  k[3] = f2b(L2); k[4] = f2b(-L1); k[5] = f2b(L0);
#pragma unroll
  for (int c = 6; c < 32; ++c) { q[c] = 0; k[c] = 0; }
}

// ---------------- fused causal attention: paired-tile dual-stream waves, tiled V ----------------
__global__ __launch_bounds__(64) void k_attn(const u16* __restrict__ Qext, const u16* __restrict__ Kext,
                                             const u16* __restrict__ Vt, u16* __restrict__ AO) {
  const int bid = blockIdx.x;                     // 1024 blocks = 16 heads x 64 pairs
  const int h = bid & 15;
  const int p = bid >> 4;                         // 0..63
  const int lane = threadIdx.x;
  const int g = lane >> 4, l15 = lane & 15;
  const int q0A = p << 4;
  const int q0B = (127 - p) << 4;
  const int qgA = q0A + l15;
  const int qgB = q0B + l15;
  const int sA = (p >> 1) + 1;                    // steps for tile A
  const int sB = ((127 - p) >> 1) + 1;            // steps for tile B (>= sA)
  const u16* Qh = Qext + (size_t)h * 2048 * 96;
  const u16* Kh = Kext + (size_t)h * 2048 * 96;
  const u16* Vh = Vt + (size_t)h * 131072;

  bf16x8 aqA[3], aqB[3];
#pragma unroll
  for (int ks = 0; ks < 3; ++ks) {
    aqA[ks] = *(const bf16x8*)(Qh + (size_t)qgA * 96 + ks * 32 + g * 8);
    aqB[ks] = *(const bf16x8*)(Qh + (size_t)qgB * 96 + ks * 32 + g * 8);
  }

  f32x4 accA[4], accB[4];
#pragma unroll
  for (int n = 0; n < 4; ++n) {
    accA[n] = (f32x4){0.f, 0.f, 0.f, 0.f};
    accB[n] = (f32x4){0.f, 0.f, 0.f, 0.f};
  }
  float lA = 0.f, lB = 0.f;

  const u16* Kbase = Kh + (size_t)l15 * 96 + g * 8;
  const int src0 = ((g & 1) << 5) + l15;
  const int src1 = src0 + 16;

  bf16x8 kX0[3], kX1[3], kY0[3], kY1[3];
#pragma unroll
  for (int ks = 0; ks < 3; ++ks) {
    kX0[ks] = *(const bf16x8*)(Kbase + ks * 32);
    kX1[ks] = *(const bf16x8*)(Kbase + 16 * 96 + ks * 32);
  }

#define GLUE(S0, S1, Q0S, QGS, LS, PBS)                                           \
  {                                                                               \
    if (jb + 31 > Q0S) {                                                          \
      _Pragma("unroll")                                                           \
      for (int r = 0; r < 4; ++r) {                                               \
        if (jb + g * 4 + r > QGS) S0[r] = -1e30f;                                 \
        if (jb + 16 + g * 4 + r > QGS) S1[r] = -1e30f;                            \
      }                                                                           \
    }                                                                             \
    _Pragma("unroll")                                                             \
    for (int r = 0; r < 4; ++r) {                                                 \
      S0[r] = exp2fast(S0[r]);                                                    \
      S1[r] = exp2fast(S1[r]);                                                    \
    }                                                                             \
    LS += ((S0[0] + S0[1]) + (S0[2] + S0[3])) + ((S1[0] + S1[1]) + (S1[2] + S1[3])); \
    const u32 w0 = pack2(S0[0], S0[1]);                                           \
    const u32 w1 = pack2(S0[2], S0[3]);                                           \
    const u32 w2 = pack2(S1[0], S1[1]);                                           \
    const u32 w3 = pack2(S1[2], S1[3]);                                           \
    const u32 a0 = (u32)__shfl((int)w0, src0);                                    \
    const u32 a1 = (u32)__shfl((int)w2, src0);                                    \
    const u32 b0 = (u32)__shfl((int)w1, src0);                                    \
    const u32 b1 = (u32)__shfl((int)w3, src0);                                    \
    const u32 c0 = (u32)__shfl((int)w0, src1);                                    \
    const u32 c1 = (u32)__shfl((int)w2, src1);                                    \
    const u32 d0 = (u32)__shfl((int)w1, src1);                                    \
    const u32 d1 = (u32)__shfl((int)w3, src1);                                    \
    PBS.u[0] = (g & 2) ? a1 : a0;                                                 \
    PBS.u[1] = (g & 2) ? b1 : b0;                                                 \
    PBS.u[2] = (g & 2) ? c1 : c0;                                                 \
    PBS.u[3] = (g & 2) ? d1 : d0;                                                 \
  }

#define ATTN_STEP(KC0, KC1, KN0, KN1)                                             \
  {                                                                               \
    const int jb = jt * 32;                                                       \
    const bool actA = (jt < sA);                                                  \
    f32x4 SB0 = (f32x4){0.f, 0.f, 0.f, 0.f}, SB1 = (f32x4){0.f, 0.f, 0.f, 0.f};   \
    f32x4 SA0 = (f32x4){0.f, 0.f, 0.f, 0.f}, SA1 = (f32x4){0.f, 0.f, 0.f, 0.f};   \
    __builtin_amdgcn_s_setprio(1);                                                \
    _Pragma("unroll")                                                             \
    for (int ks = 0; ks < 3; ++ks) {                                              \
      SB0 = MFMA16(KC0[ks], aqB[ks], SB0);                                        \
      SB1 = MFMA16(KC1[ks], aqB[ks], SB1);                                        \
    }                                                                             \
    if (actA) {                                                                   \
      _Pragma("unroll")                                                           \
      for (int ks = 0; ks < 3; ++ks) {                                            \
        SA0 = MFMA16(KC0[ks], aqA[ks], SA0);                                      \
        SA1 = MFMA16(KC1[ks], aqA[ks], SA1);                                      \
      }                                                                           \
    }                                                                             \
    __builtin_amdgcn_s_setprio(0);                                                \
    bf16x8 av[4];  /* shared V from tiled layout: 4KB contiguous tile */          \
    _Pragma("unroll")                                                             \
    for (int n = 0; n < 4; ++n)                                                   \
      av[n] = *(const bf16x8*)(Vh + (size_t)jb * 64 + (n * 16 + l15) * 32 + g * 8); \
    const int jbn = (jt + 1 < sB) ? jb + 32 : jb;  /* shared K prefetch */        \
    const u16* kp = Kbase + (size_t)jbn * 96;                                     \
    _Pragma("unroll")                                                             \
    for (int ks = 0; ks < 3; ++ks) {                                              \
      KN0[ks] = *(const bf16x8*)(kp + ks * 32);                                   \
      KN1[ks] = *(const bf16x8*)(kp + 16 * 96 + ks * 32);                         \
    }                                                                             \
    union { u32 u[4]; bf16x8 bv; } pbB, pbA;                                      \
    GLUE(SB0, SB1, q0B, qgB, lB, pbB);                                            \
    if (actA) GLUE(SA0, SA1, q0A, qgA, lA, pbA);                                  \
    __builtin_amdgcn_s_setprio(1);                                                \
    _Pragma("unroll")                                                             \
    for (int n = 0; n < 4; ++n) accB[n] = MFMA16(av[n], pbB.bv, accB[n]);         \
    if (actA) {                                                                   \
      _Pragma("unroll")                                                           \
      for (int n = 0; n < 4; ++n) accA[n] = MFMA16(av[n], pbA.bv, accA[n]);       \
    }                                                                             \
    __builtin_amdgcn_s_setprio(0);                                                \
  }

  int jt = 0;
  for (;;) {
    ATTN_STEP(kX0, kX1, kY0, kY1);
    if (++jt >= sB) break;
    ATTN_STEP(kY0, kY1, kX0, kX1);
    if (++jt >= sB) break;
  }
#undef ATTN_STEP
#undef GLUE

  // epilogue: reduce row-sum partials across the 4 g-groups, normalize, store (both streams)
  lA += __shfl_xor(lA, 16);
  lA += __shfl_xor(lA, 32);
  lB += __shfl_xor(lB, 16);
  lB += __shfl_xor(lB, 32);
  const float invA = 1.0f / lA;
  const float invB = 1.0f / lB;
  u32* dstA = (u32*)(AO + (size_t)qgA * 1024 + h * 64 + g * 4);
  u32* dstB = (u32*)(AO + (size_t)qgB * 1024 + h * 64 + g * 4);
#pragma unroll
  for (int n = 0; n < 4; ++n) {
    dstA[n * 8 + 0] = pack2(accA[n][0] * invA, accA[n][1] * invA);
    dstA[n * 8 + 1] = pack2(accA[n][2] * invA, accA[n][3] * invA);
    dstB[n * 8 + 0] = pack2(accB[n][0] * invB, accB[n][1] * invB);
    dstB[n * 8 + 1] = pack2(accB[n][2] * invB, accB[n][3] * invB);
  }
}

// ---------------- GEMM out: AO @ WoutT + bout  (M=2048, N=1024, K=1024) ----------------
__global__ __launch_bounds__(256) void k_gemm_out(const u16* __restrict__ AO, const u16* __restrict__ WoT,
                                                  const float* __restrict__ bout, float* __restrict__ out) {
  __shared__ __align__(16) u16 ldsA[128 * 64];
  __shared__ __align__(16) u16 ldsB[64 * 64];
  const int bid = blockIdx.x;                     // 256 blocks
  const int bn = bid & 15, bm = bid >> 4;
  f32x4 acc[4][2];
#pragma unroll
  for (int m = 0; m < 4; ++m)
#pragma unroll
    for (int n = 0; n < 2; ++n) acc[m][n] = (f32x4){0.f, 0.f, 0.f, 0.f};
  gemm_core_128x64(AO, WoT, bm * 128, bn * 64, 1024, ldsA, ldsB, acc);

  const int tid = threadIdx.x;
  const int wave = tid >> 6, lane = tid & 63;
  const int wr = wave >> 1, wc = wave & 1;
  const int g = lane >> 4, l15 = lane & 15;
  const int tbase = bm * 128 + wr * 64 + g * 4;
  const int cbase = bn * 64 + wc * 32 + l15;
#pragma unroll
  for (int m = 0; m < 4; ++m)
#pragma unroll
    for (int n = 0; n < 2; ++n) {
      const int c = cbase + n * 16;
      const float bb = bout[c];
#pragma unroll
      for (int r = 0; r < 4; ++r) {
        const int t = tbase + m * 16 + r;
        out[(size_t)t * 1024 + c] = acc[m][n][r] + bb;
      }
    }
}

// ---------------- launch ----------------
extern "C" void kernel_launch(void* const* d_in, const int* in_sizes, int n_in,
                              void* d_out, int out_size, void* d_ws, size_t ws_size,
                              hipStream_t stream) {
  const float* x      = (const float*)d_in[0];
  const float* Wqkv   = (const float*)d_in[1];
  const float* bqkv   = (const float*)d_in[2];
  const float* W1p    = (const float*)d_in[3];
  const float* W2p    = (const float*)d_in[4];
  const float* pscale = (const float*)d_in[5];
  const float* Wout   = (const float*)d_in[6];
  const float* bout   = (const float*)d_in[7];
  float* out = (float*)d_out;

  char* ws = (char*)d_ws;
  u16*   WB    = (u16*)(ws + 0);          // [3200][1024] bf16
  u16*   WoT   = (u16*)(ws + 6553600);    // [1024][1024] bf16
  u16*   xb    = (u16*)(ws + 8650752);    // [2048][1024] bf16
  u16*   Qext  = (u16*)(ws + 12845056);   // [16][2048][96] bf16 (q*0.1803 | s*log2e*L | 0)
  u16*   Kext  = (u16*)(ws + 19136512);   // [16][2048][96] bf16 (k | J·L | 0)
  u16*   Vt    = (u16*)(ws + 25427968);   // [16][64][64][32] bf16 (tiled V^T)
  float* P12   = (float*)(ws + 29622272); // [2048][128] f32
  u16*   AO    = (u16*)(ws + 30670848);   // [2048][1024] bf16

  k_prep<<<6656, 256, 0, stream>>>(Wqkv, Wout, W1p, W2p, x, WB, WoT, xb);
  k_gemm_qkvp<<<800, 256, 0, stream>>>(xb, WB, bqkv, Qext, Kext, Vt, P12);
  k_lines<<<128, 256, 0, stream>>>(P12, pscale, Qext, Kext);
  k_attn<<<1024, 64, 0, stream>>>(Qext, Kext, Vt, AO);
  k_gemm_out<<<256, 256, 0, stream>>>(AO, WoT, bout, out);
}

// Round 10
// 97.206 us; speedup vs baseline: 1.2127x; 1.0497x over previous
//
#include <hip/hip_runtime.h>

typedef unsigned short u16;
typedef unsigned int u32;
typedef __attribute__((ext_vector_type(8))) __bf16 bf16x8;
typedef __attribute__((ext_vector_type(4))) float f32x4;
typedef __attribute__((ext_vector_type(4))) u16 u16x4;

#define MFMA16(a, b, c) __builtin_amdgcn_mfma_f32_16x16x32_bf16((a), (b), (c), 0, 0, 0)

static __device__ __forceinline__ u16 f2b(float f) {
  union { float f; u32 u; } v; v.f = f;
  u32 u = v.u;
  return (u16)((u + 0x7FFFu + ((u >> 16) & 1u)) >> 16);
}

// packed f32x2 -> bf16x2 (RNE), low half = a
static __device__ __forceinline__ u32 pack2(float a, float b) {
  u32 r;
  asm("v_cvt_pk_bf16_f32 %0, %1, %2" : "=v"(r) : "v"(a), "v"(b));
  return r;
}

static __device__ __forceinline__ float exp2fast(float x) {
#if defined(__has_builtin) && __has_builtin(__builtin_amdgcn_exp2f)
  return __builtin_amdgcn_exp2f(x);
#else
  return __expf(x * 0.6931471805599453f);
#endif
}

static __device__ __forceinline__ void gload16(const u16* gp, u16* lp) {
  __builtin_amdgcn_global_load_lds((__attribute__((address_space(1))) void*)(u16*)gp,
                                   (__attribute__((address_space(3))) void*)lp, 16, 0, 0);
}

// ---------------- merged prep kernel ----------------
__global__ __launch_bounds__(256) void k_prep(const float* __restrict__ Wqkv, const float* __restrict__ Wout,
                                              const float* __restrict__ W1p, const float* __restrict__ W2p,
                                              const float* __restrict__ x,
                                              u16* __restrict__ WB, u16* __restrict__ WoT,
                                              u16* __restrict__ xb) {
  const int b = blockIdx.x;
  const int t = threadIdx.x;
  if (b < 4096) {
    __shared__ float tile[32][33];
    const float* src; u16* dst; int N, n0, k0;
    if (b < 3072) { src = Wqkv; dst = WB;  N = 3072; n0 = (b % 96) * 32; k0 = (b / 96) * 32; }
    else { const int bb = b - 3072; src = Wout; dst = WoT; N = 1024; n0 = (bb & 31) * 32; k0 = (bb >> 5) * 32; }
    const int r = t >> 3, c4 = (t & 7) << 2;
    const float4 in4 = *(const float4*)(src + (size_t)(k0 + r) * N + n0 + c4);
    tile[r][c4 + 0] = in4.x; tile[r][c4 + 1] = in4.y;
    tile[r][c4 + 2] = in4.z; tile[r][c4 + 3] = in4.w;
    __syncthreads();
    u16x4 o;
    o.x = f2b(tile[c4 + 0][r]); o.y = f2b(tile[c4 + 1][r]);
    o.z = f2b(tile[c4 + 2][r]); o.w = f2b(tile[c4 + 3][r]);
    *(u16x4*)(dst + (size_t)(n0 + r) * 1024 + k0 + c4) = o;
  } else if (b < 4608) {
    const int idx = (b - 4096) * 256 + t;  // 131072
    const int j = idx >> 10, k = idx & 1023;
    const float v = (j < 64) ? W1p[(size_t)k * 64 + j] : W2p[(size_t)k * 64 + (j - 64)];
    WB[(size_t)3072 * 1024 + idx] = f2b(v);
  } else {
    const size_t idx = ((size_t)(b - 4608) * 256 + t) << 2;
    const float4 v = *(const float4*)(x + idx);
    u16x4 o; o.x = f2b(v.x); o.y = f2b(v.y); o.z = f2b(v.z); o.w = f2b(v.w);
    *(u16x4*)(xb + idx) = o;
  }
}

// ---------------- 128x64 bf16 MFMA GEMM core (BK=64, global_load_lds, XOR swizzle) ----------------
static __device__ __forceinline__ void gemm_core_128x64(const u16* __restrict__ A, const u16* __restrict__ B,
                                                        int brow, int bcol, int K,
                                                        u16* ldsA, u16* ldsB, f32x4 acc[4][2]) {
  const int tid = threadIdx.x;
  const int wave = tid >> 6, lane = tid & 63;
  const int wr = wave >> 1, wc = wave & 1;
  const int g = lane >> 4, l15 = lane & 15;

  for (int k0 = 0; k0 < K; k0 += 64) {
#pragma unroll
    for (int li = 0; li < 4; ++li) {
      const int f = li * 256 + wave * 64 + lane;
      const int row = f >> 3;
      const int slot = f & 7;
      const int gcol = ((slot ^ (row & 7)) << 3);
      gload16(A + (size_t)(brow + row) * K + k0 + gcol, ldsA + (size_t)(li * 256 + wave * 64) * 8);
    }
#pragma unroll
    for (int li = 0; li < 2; ++li) {
      const int f = li * 256 + wave * 64 + lane;
      const int row = f >> 3;
      const int slot = f & 7;
      const int gcol = ((slot ^ (row & 7)) << 3);
      gload16(B + (size_t)(bcol + row) * K + k0 + gcol, ldsB + (size_t)(li * 256 + wave * 64) * 8);
    }
    __syncthreads();
    bf16x8 af[4][2], bfr[2][2];
#pragma unroll
    for (int kk = 0; kk < 2; ++kk) {
#pragma unroll
      for (int m = 0; m < 4; ++m) {
        const int rowA = wr * 64 + m * 16 + l15;
        const int chA = (kk * 4 + g) ^ (rowA & 7);
        af[m][kk] = *(const bf16x8*)(ldsA + (size_t)rowA * 64 + chA * 8);
      }
#pragma unroll
      for (int n = 0; n < 2; ++n) {
        const int rowB = wc * 32 + n * 16 + l15;
        const int chB = (kk * 4 + g) ^ (rowB & 7);
        bfr[n][kk] = *(const bf16x8*)(ldsB + (size_t)rowB * 64 + chB * 8);
      }
    }
#pragma unroll
    for (int m = 0; m < 4; ++m)
#pragma unroll
      for (int n = 0; n < 2; ++n)
#pragma unroll
        for (int kk = 0; kk < 2; ++kk)
          acc[m][n] = MFMA16(af[m][kk], bfr[n][kk], acc[m][n]);
    __syncthreads();
  }
}

// ---------------- GEMM1: x @ [Wqkv|W1p|W2p]  (M=2048, N=3200, K=1024), 128x64 tile ----------------
// Q prescale = 0.125 * log2(e); V stored TILED: Vt[h][jt][d][tin] = [h][64][64][32]
__global__ __launch_bounds__(256) void k_gemm_qkvp(const u16* __restrict__ xb, const u16* __restrict__ WB,
                                                   const float* __restrict__ bqkv,
                                                   u16* __restrict__ Qext, u16* __restrict__ Kext,
                                                   u16* __restrict__ Vt, float* __restrict__ P12) {
  __shared__ __align__(16) u16 ldsA[128 * 64];
  __shared__ __align__(16) u16 ldsB[64 * 64];
  const int bid = blockIdx.x;                      // 800 blocks
  const int bn = bid % 50, bm = bid / 50;
  f32x4 acc[4][2];
#pragma unroll
  for (int m = 0; m < 4; ++m)
#pragma unroll
    for (int n = 0; n < 2; ++n) acc[m][n] = (f32x4){0.f, 0.f, 0.f, 0.f};
  gemm_core_128x64(xb, WB, bm * 128, bn * 64, 1024, ldsA, ldsB, acc);

  const int tid = threadIdx.x;
  const int wave = tid >> 6, lane = tid & 63;
  const int wr = wave >> 1, wc = wave & 1;
  const int g = lane >> 4, l15 = lane & 15;
  const int tbase = bm * 128 + wr * 64 + g * 4;
  const int cbase = bn * 64 + wc * 32 + l15;
#pragma unroll
  for (int m = 0; m < 4; ++m) {
#pragma unroll
    for (int n = 0; n < 2; ++n) {
      const int c = cbase + n * 16;
#pragma unroll
      for (int r = 0; r < 4; ++r) {
        const int t = tbase + m * 16 + r;
        float v = acc[m][n][r];
        if (c < 3072) {
          v += bqkv[c];
          const int sub = c >> 10;
          const int rem = c & 1023;
          const int hh = rem >> 6, d = rem & 63;
          if (sub == 0)      Qext[((size_t)hh * 2048 + t) * 96 + d] = f2b(v * 0.18033688f);
          else if (sub == 1) Kext[((size_t)hh * 2048 + t) * 96 + d] = f2b(v);
          else               Vt[(size_t)hh * 131072 + (size_t)(t >> 5) * 2048 + d * 32 + (t & 31)] = f2b(v);
        } else {
          P12[(size_t)t * 128 + (c - 3072)] = v;
        }
      }
    }
  }
}

// ---------------- Plucker lines -> Qext/Kext cols 64..95 ----------------
__global__ __launch_bounds__(256) void k_lines(const float* __restrict__ P12, const float* __restrict__ pscale,
                                               u16* __restrict__ Qext, u16* __restrict__ Kext) {
  const int idx = blockIdx.x * 256 + threadIdx.x;  // 32768 = 2048*16
  const int t = idx >> 4, h = idx & 15;
  const float* p = P12 + (size_t)t * 128;
  const float a0 = p[h * 4 + 0], a1 = p[h * 4 + 1], a2 = p[h * 4 + 2], a3 = p[h * 4 + 3];
  const float b0 = p[64 + h * 4 + 0], b1 = p[64 + h * 4 + 1], b2 = p[64 + h * 4 + 2], b3 = p[64 + h * 4 + 3];
  float L0 = a0 * b1 - a1 * b0;
  float L1 = a0 * b2 - a2 * b0;
  float L2 = a0 * b3 - a3 * b0;
  float L3 = a1 * b2 - a2 * b1;
  float L4 = a1 * b3 - a3 * b1;
  float L5 = a2 * b3 - a3 * b2;
  const float nrm = sqrtf(L0 * L0 + L1 * L1 + L2 * L2 + L3 * L3 + L4 * L4 + L5 * L5);
  const float inv = 1.0f / fmaxf(nrm, 1e-12f);
  L0 *= inv; L1 *= inv; L2 *= inv; L3 *= inv; L4 *= inv; L5 *= inv;
  const float s = pscale[h] * 1.44269504f;  // fold log2(e) into q-side bias
  u16* q = Qext + ((size_t)h * 2048 + t) * 96 + 64;
  u16* k = Kext + ((size_t)h * 2048 + t) * 96 + 64;
  q[0] = f2b(L0 * s); q[1] = f2b(L1 * s); q[2] = f2b(L2 * s);
  q[3] = f2b(L3 * s); q[4] = f2b(L4 * s); q[5] = f2b(L5 * s);
  // Jlines = J6 @ L : [L5, -L4, L3, L2, -L1, L0]
  k[0] = f2b(L5); k[1] = f2b(-L4); k[2] = f2b(L3);
  k[3] = f2b(L2); k[4] = f2b(-L1); k[5] = f2b(L0);
#pragma unroll
  for (int c = 6; c < 32; ++c) { q[c] = 0; k[c] = 0; }
}

// ---------------- fused causal attention: paired dual-stream + software-pipelined step ----------------
// Pipeline (ONE change vs R9): iteration jt computes S(jt+1) from K-regs loaded a step ago
// (its MFMA latency hides under GLUE(jt)), prefetches K(jt+2) and V(jt+1) (a full step before
// use), then GLUE(jt) on ready S, then PV(jt) on V loaded a step ago. No exposed waits.
__global__ __launch_bounds__(64) void k_attn(const u16* __restrict__ Qext, const u16* __restrict__ Kext,
                                             const u16* __restrict__ Vt, u16* __restrict__ AO) {
  const int bid = blockIdx.x;                     // 1024 blocks = 16 heads x 64 pairs
  const int h = bid & 15;
  const int p = bid >> 4;                         // 0..63
  const int lane = threadIdx.x;
  const int g = lane >> 4, l15 = lane & 15;
  const int q0A = p << 4;
  const int q0B = (127 - p) << 4;
  const int qgA = q0A + l15;
  const int qgB = q0B + l15;
  const int sA = (p >> 1) + 1;                    // steps for tile A
  const int sB = ((127 - p) >> 1) + 1;            // steps for tile B (>= sA+1 always)
  const u16* Qh = Qext + (size_t)h * 2048 * 96;
  const u16* Kh = Kext + (size_t)h * 2048 * 96;
  const u16* Vh = Vt + (size_t)h * 131072;

  bf16x8 aqA[3], aqB[3];
#pragma unroll
  for (int ks = 0; ks < 3; ++ks) {
    aqA[ks] = *(const bf16x8*)(Qh + (size_t)qgA * 96 + ks * 32 + g * 8);
    aqB[ks] = *(const bf16x8*)(Qh + (size_t)qgB * 96 + ks * 32 + g * 8);
  }

  f32x4 accA[4], accB[4];
#pragma unroll
  for (int n = 0; n < 4; ++n) {
    accA[n] = (f32x4){0.f, 0.f, 0.f, 0.f};
    accB[n] = (f32x4){0.f, 0.f, 0.f, 0.f};
  }
  float lA = 0.f, lB = 0.f;

  const u16* Kbase = Kh + (size_t)l15 * 96 + g * 8;
  const u16* Vlane = Vh + (size_t)l15 * 32 + g * 8;   // + jt*2048 + n*512
  const int src0 = ((g & 1) << 5) + l15;
  const int src1 = src0 + 16;

  bf16x8 kX0[3], kX1[3], kY0[3], kY1[3];
  bf16x8 avX[4], avY[4];
  f32x4 SA0c, SA1c, SB0c, SB1c, SA0n, SA1n, SB0n, SB1n;

  // ---- prologue: K(0)->kX, S(0), K(1)->kY, V(0)->avX
  {
#pragma unroll
    for (int ks = 0; ks < 3; ++ks) {
      kX0[ks] = *(const bf16x8*)(Kbase + ks * 32);
      kX1[ks] = *(const bf16x8*)(Kbase + 16 * 96 + ks * 32);
    }
    SB0c = (f32x4){0.f, 0.f, 0.f, 0.f}; SB1c = SB0c; SA0c = SB0c; SA1c = SB0c;
#pragma unroll
    for (int ks = 0; ks < 3; ++ks) {
      SB0c = MFMA16(kX0[ks], aqB[ks], SB0c);
      SB1c = MFMA16(kX1[ks], aqB[ks], SB1c);
      SA0c = MFMA16(kX0[ks], aqA[ks], SA0c);
      SA1c = MFMA16(kX1[ks], aqA[ks], SA1c);
    }
    const u16* kp = Kbase + (size_t)((1 < sB) ? 1 : 0) * 32 * 96;
#pragma unroll
    for (int ks = 0; ks < 3; ++ks) {
      kY0[ks] = *(const bf16x8*)(kp + ks * 32);
      kY1[ks] = *(const bf16x8*)(kp + 16 * 96 + ks * 32);
    }
#pragma unroll
    for (int n = 0; n < 4; ++n) avX[n] = *(const bf16x8*)(Vlane + n * 512);
  }

#define GLUE(S0, S1, Q0S, QGS, LS, PBS)                                           \
  {                                                                               \
    if (jb + 31 > Q0S) {                                                          \
      _Pragma("unroll")                                                           \
      for (int r = 0; r < 4; ++r) {                                               \
        if (jb + g * 4 + r > QGS) S0[r] = -1e30f;                                 \
        if (jb + 16 + g * 4 + r > QGS) S1[r] = -1e30f;                            \
      }                                                                           \
    }                                                                             \
    _Pragma("unroll")                                                             \
    for (int r = 0; r < 4; ++r) {                                                 \
      S0[r] = exp2fast(S0[r]);                                                    \
      S1[r] = exp2fast(S1[r]);                                                    \
    }                                                                             \
    LS += ((S0[0] + S0[1]) + (S0[2] + S0[3])) + ((S1[0] + S1[1]) + (S1[2] + S1[3])); \
    const u32 w0 = pack2(S0[0], S0[1]);                                           \
    const u32 w1 = pack2(S0[2], S0[3]);                                           \
    const u32 w2 = pack2(S1[0], S1[1]);                                           \
    const u32 w3 = pack2(S1[2], S1[3]);                                           \
    const u32 a0 = (u32)__shfl((int)w0, src0);                                    \
    const u32 a1 = (u32)__shfl((int)w2, src0);                                    \
    const u32 b0 = (u32)__shfl((int)w1, src0);                                    \
    const u32 b1 = (u32)__shfl((int)w3, src0);                                    \
    const u32 c0 = (u32)__shfl((int)w0, src1);                                    \
    const u32 c1 = (u32)__shfl((int)w2, src1);                                    \
    const u32 d0 = (u32)__shfl((int)w1, src1);                                    \
    const u32 d1 = (u32)__shfl((int)w3, src1);                                    \
    PBS.u[0] = (g & 2) ? a1 : a0;                                                 \
    PBS.u[1] = (g & 2) ? b1 : b0;                                                 \
    PBS.u[2] = (g & 2) ? c1 : c0;                                                 \
    PBS.u[3] = (g & 2) ? d1 : d0;                                                 \
  }

  // STEP for iteration jt: S_cur = S(jt) ready; KN holds K(jt+1); KL gets K(jt+2);
  // AVC = V(jt) ready; AVN gets V(jt+1).
#define ATTN_STEP(SA0C, SA1C, SB0C, SB1C, SA0N, SA1N, SB0N, SB1N, KN0, KN1, KL0, KL1, AVC, AVN) \
  {                                                                               \
    const int jb = jt * 32;                                                       \
    const int jn1 = (jt + 1 < sB) ? jt + 1 : jt;                                  \
    const int jn2 = (jt + 2 < sB) ? jt + 2 : jt;                                  \
    /* 1: S(jt+1) from K-regs loaded last step */                                 \
    SB0N = (f32x4){0.f, 0.f, 0.f, 0.f}; SB1N = SB0N;                              \
    __builtin_amdgcn_s_setprio(1);                                                \
    _Pragma("unroll")                                                             \
    for (int ks = 0; ks < 3; ++ks) {                                              \
      SB0N = MFMA16(KN0[ks], aqB[ks], SB0N);                                      \
      SB1N = MFMA16(KN1[ks], aqB[ks], SB1N);                                      \
    }                                                                             \
    if (jt + 1 < sA) {                                                            \
      SA0N = (f32x4){0.f, 0.f, 0.f, 0.f}; SA1N = SA0N;                            \
      _Pragma("unroll")                                                           \
      for (int ks = 0; ks < 3; ++ks) {                                            \
        SA0N = MFMA16(KN0[ks], aqA[ks], SA0N);                                    \
        SA1N = MFMA16(KN1[ks], aqA[ks], SA1N);                                    \
      }                                                                           \
    }                                                                             \
    __builtin_amdgcn_s_setprio(0);                                                \
    /* 2: prefetch K(jt+2) */                                                     \
    const u16* kp = Kbase + (size_t)jn2 * 32 * 96;                                \
    _Pragma("unroll")                                                             \
    for (int ks = 0; ks < 3; ++ks) {                                              \
      KL0[ks] = *(const bf16x8*)(kp + ks * 32);                                   \
      KL1[ks] = *(const bf16x8*)(kp + 16 * 96 + ks * 32);                         \
    }                                                                             \
    /* 3: prefetch V(jt+1) */                                                     \
    _Pragma("unroll")                                                             \
    for (int n = 0; n < 4; ++n)                                                   \
      AVN[n] = *(const bf16x8*)(Vlane + (size_t)jn1 * 2048 + n * 512);            \
    /* 4: GLUE on ready S(jt) */                                                  \
    union { u32 u[4]; bf16x8 bv; } pbB, pbA;                                      \
    GLUE(SB0C, SB1C, q0B, qgB, lB, pbB);                                          \
    const bool actA = (jt < sA);                                                  \
    if (actA) GLUE(SA0C, SA1C, q0A, qgA, lA, pbA);                                \
    /* 5: PV on V loaded last step */                                             \
    __builtin_amdgcn_s_setprio(1);                                                \
    _Pragma("unroll")                                                             \
    for (int n = 0; n < 4; ++n) accB[n] = MFMA16(AVC[n], pbB.bv, accB[n]);        \
    if (actA) {                                                                   \
      _Pragma("unroll")                                                           \
      for (int n = 0; n < 4; ++n) accA[n] = MFMA16(AVC[n], pbA.bv, accA[n]);      \
    }                                                                             \
    __builtin_amdgcn_s_setprio(0);                                                \
  }

  int jt = 0;
  for (;;) {
    ATTN_STEP(SA0c, SA1c, SB0c, SB1c, SA0n, SA1n, SB0n, SB1n, kY0, kY1, kX0, kX1, avX, avY);
    if (++jt >= sB) break;
    ATTN_STEP(SA0n, SA1n, SB0n, SB1n, SA0c, SA1c, SB0c, SB1c, kX0, kX1, kY0, kY1, avY, avX);
    if (++jt >= sB) break;
  }
#undef ATTN_STEP
#undef GLUE

  // epilogue: reduce row-sum partials across the 4 g-groups, normalize, store (both streams)
  lA += __shfl_xor(lA, 16);
  lA += __shfl_xor(lA, 32);
  lB += __shfl_xor(lB, 16);
  lB += __shfl_xor(lB, 32);
  const float invA = 1.0f / lA;
  const float invB = 1.0f / lB;
  u32* dstA = (u32*)(AO + (size_t)qgA * 1024 + h * 64 + g * 4);
  u32* dstB = (u32*)(AO + (size_t)qgB * 1024 + h * 64 + g * 4);
#pragma unroll
  for (int n = 0; n < 4; ++n) {
    dstA[n * 8 + 0] = pack2(accA[n][0] * invA, accA[n][1] * invA);
    dstA[n * 8 + 1] = pack2(accA[n][2] * invA, accA[n][3] * invA);
    dstB[n * 8 + 0] = pack2(accB[n][0] * invB, accB[n][1] * invB);
    dstB[n * 8 + 1] = pack2(accB[n][2] * invB, accB[n][3] * invB);
  }
}

// ---------------- GEMM out: AO @ WoutT + bout  (M=2048, N=1024, K=1024), 128x32 tile ----------------
__global__ __launch_bounds__(256) void k_gemm_out(const u16* __restrict__ AO, const u16* __restrict__ WoT,
                                                  const float* __restrict__ bout, float* __restrict__ out) {
  __shared__ __align__(16) u16 ldsA[128 * 64];
  __shared__ __align__(16) u16 ldsB[32 * 64];
  const int bid = blockIdx.x;                     // 512 blocks = 2/CU
  const int bn = bid & 31, bm = bid >> 5;
  const int tid = threadIdx.x;
  const int wave = tid >> 6, lane = tid & 63;
  const int wr = wave >> 1, wc = wave & 1;
  const int g = lane >> 4, l15 = lane & 15;

  f32x4 acc[4];
#pragma unroll
  for (int m = 0; m < 4; ++m) acc[m] = (f32x4){0.f, 0.f, 0.f, 0.f};

  for (int k0 = 0; k0 < 1024; k0 += 64) {
#pragma unroll
    for (int li = 0; li < 4; ++li) {
      const int f = li * 256 + wave * 64 + lane;
      const int row = f >> 3;
      const int slot = f & 7;
      const int gcol = ((slot ^ (row & 7)) << 3);
      gload16(AO + (size_t)(bm * 128 + row) * 1024 + k0 + gcol, ldsA + (size_t)(li * 256 + wave * 64) * 8);
    }
    {
      const int f = wave * 64 + lane;            // 256 chunks = 32 rows x 64 cols
      const int row = f >> 3;
      const int slot = f & 7;
      const int gcol = ((slot ^ (row & 7)) << 3);
      gload16(WoT + (size_t)(bn * 32 + row) * 1024 + k0 + gcol, ldsB + (size_t)(wave * 64) * 8);
    }
    __syncthreads();
    bf16x8 af[4][2], bfr[2];
#pragma unroll
    for (int kk = 0; kk < 2; ++kk) {
#pragma unroll
      for (int m = 0; m < 4; ++m) {
        const int rowA = wr * 64 + m * 16 + l15;
        const int chA = (kk * 4 + g) ^ (rowA & 7);
        af[m][kk] = *(const bf16x8*)(ldsA + (size_t)rowA * 64 + chA * 8);
      }
      const int rowB = wc * 16 + l15;
      const int chB = (kk * 4 + g) ^ (rowB & 7);
      bfr[kk] = *(const bf16x8*)(ldsB + (size_t)rowB * 64 + chB * 8);
    }
#pragma unroll
    for (int m = 0; m < 4; ++m)
#pragma unroll
      for (int kk = 0; kk < 2; ++kk)
        acc[m] = MFMA16(af[m][kk], bfr[kk], acc[m]);
    __syncthreads();
  }

  const int tbase = bm * 128 + wr * 64 + g * 4;
  const int c = bn * 32 + wc * 16 + l15;
  const float bb = bout[c];
#pragma unroll
  for (int m = 0; m < 4; ++m)
#pragma unroll
    for (int r = 0; r < 4; ++r) {
      const int t = tbase + m * 16 + r;
      out[(size_t)t * 1024 + c] = acc[m][r] + bb;
    }
}

// ---------------- launch ----------------
extern "C" void kernel_launch(void* const* d_in, const int* in_sizes, int n_in,
                              void* d_out, int out_size, void* d_ws, size_t ws_size,
                              hipStream_t stream) {
  const float* x      = (const float*)d_in[0];
  const float* Wqkv   = (const float*)d_in[1];
  const float* bqkv   = (const float*)d_in[2];
  const float* W1p    = (const float*)d_in[3];
  const float* W2p    = (const float*)d_in[4];
  const float* pscale = (const float*)d_in[5];
  const float* Wout   = (const float*)d_in[6];
  const float* bout   = (const float*)d_in[7];
  float* out = (float*)d_out;

  char* ws = (char*)d_ws;
  u16*   WB    = (u16*)(ws + 0);          // [3200][1024] bf16
  u16*   WoT   = (u16*)(ws + 6553600);    // [1024][1024] bf16
  u16*   xb    = (u16*)(ws + 8650752);    // [2048][1024] bf16
  u16*   Qext  = (u16*)(ws + 12845056);   // [16][2048][96] bf16 (q*0.1803 | s*log2e*L | 0)
  u16*   Kext  = (u16*)(ws + 19136512);   // [16][2048][96] bf16 (k | J·L | 0)
  u16*   Vt    = (u16*)(ws + 25427968);   // [16][64][64][32] bf16 (tiled V^T)
  float* P12   = (float*)(ws + 29622272); // [2048][128] f32
  u16*   AO    = (u16*)(ws + 30670848);   // [2048][1024] bf16

  k_prep<<<6656, 256, 0, stream>>>(Wqkv, Wout, W1p, W2p, x, WB, WoT, xb);
  k_gemm_qkvp<<<800, 256, 0, stream>>>(xb, WB, bqkv, Qext, Kext, Vt, P12);
  k_lines<<<128, 256, 0, stream>>>(P12, pscale, Qext, Kext);
  k_attn<<<1024, 64, 0, stream>>>(Qext, Kext, Vt, AO);
  k_gemm_out<<<512, 256, 0, stream>>>(AO, WoT, bout, out);
}

// Round 11
// 97.083 us; speedup vs baseline: 1.2142x; 1.0013x over previous
//
#include <hip/hip_runtime.h>

typedef unsigned short u16;
typedef unsigned int u32;
typedef __attribute__((ext_vector_type(8))) __bf16 bf16x8;
typedef __attribute__((ext_vector_type(4))) float f32x4;
typedef __attribute__((ext_vector_type(4))) u16 u16x4;

#define MFMA16(a, b, c) __builtin_amdgcn_mfma_f32_16x16x32_bf16((a), (b), (c), 0, 0, 0)

static __device__ __forceinline__ u16 f2b(float f) {
  union { float f; u32 u; } v; v.f = f;
  u32 u = v.u;
  return (u16)((u + 0x7FFFu + ((u >> 16) & 1u)) >> 16);
}

// packed f32x2 -> bf16x2 (RNE), low half = a
static __device__ __forceinline__ u32 pack2(float a, float b) {
  u32 r;
  asm("v_cvt_pk_bf16_f32 %0, %1, %2" : "=v"(r) : "v"(a), "v"(b));
  return r;
}

static __device__ __forceinline__ float exp2fast(float x) {
#if defined(__has_builtin) && __has_builtin(__builtin_amdgcn_exp2f)
  return __builtin_amdgcn_exp2f(x);
#else
  return __expf(x * 0.6931471805599453f);
#endif
}

static __device__ __forceinline__ void gload16(const u16* gp, u16* lp) {
  __builtin_amdgcn_global_load_lds((__attribute__((address_space(1))) void*)(u16*)gp,
                                   (__attribute__((address_space(3))) void*)lp, 16, 0, 0);
}

// ---------------- merged prep kernel ----------------
// blocks [0,768): Wqkv [1024][3072] -> WB transpose (64x64 tiles, 16B writes)
// blocks [768,1024): Wout -> WoT transpose
// blocks [1024,1536): W1p/W2p -> WB rows 3072..3199
// blocks [1536,3584): x f32 -> xb bf16
__global__ __launch_bounds__(256) void k_prep(const float* __restrict__ Wqkv, const float* __restrict__ Wout,
                                              const float* __restrict__ W1p, const float* __restrict__ W2p,
                                              const float* __restrict__ x,
                                              u16* __restrict__ WB, u16* __restrict__ WoT,
                                              u16* __restrict__ xb) {
  const int b = blockIdx.x;
  const int t = threadIdx.x;
  if (b < 1024) {
    __shared__ float tile[64][65];
    const float* src; u16* dst; int N, n0, k0;
    if (b < 768) { src = Wqkv; dst = WB;  N = 3072; n0 = (b % 48) * 64; k0 = (b / 48) * 64; }
    else { const int bb = b - 768; src = Wout; dst = WoT; N = 1024; n0 = (bb & 15) * 64; k0 = (bb >> 4) * 64; }
    const int rr = t >> 4, cc = (t & 15) << 2;
#pragma unroll
    for (int i = 0; i < 4; ++i) {
      const float4 v = *(const float4*)(src + (size_t)(k0 + rr + i * 16) * N + n0 + cc);
      tile[rr + i * 16][cc + 0] = v.x; tile[rr + i * 16][cc + 1] = v.y;
      tile[rr + i * 16][cc + 2] = v.z; tile[rr + i * 16][cc + 3] = v.w;
    }
    __syncthreads();
    const int nr = t >> 3, kc = (t & 7) << 3;
#pragma unroll
    for (int i = 0; i < 2; ++i) {
      u16 o[8];
#pragma unroll
      for (int j = 0; j < 8; ++j) o[j] = f2b(tile[kc + j][nr + i * 32]);
      *(uint4*)(dst + (size_t)(n0 + nr + i * 32) * 1024 + k0 + kc) = *(const uint4*)o;
    }
  } else if (b < 1536) {
    const int idx = (b - 1024) * 256 + t;  // 131072
    const int j = idx >> 10, k = idx & 1023;
    const float v = (j < 64) ? W1p[(size_t)k * 64 + j] : W2p[(size_t)k * 64 + (j - 64)];
    WB[(size_t)3072 * 1024 + idx] = f2b(v);
  } else {
    const size_t idx = ((size_t)(b - 1536) * 256 + t) << 2;
    const float4 v = *(const float4*)(x + idx);
    u16x4 o; o.x = f2b(v.x); o.y = f2b(v.y); o.z = f2b(v.z); o.w = f2b(v.w);
    *(u16x4*)(xb + idx) = o;
  }
}

// ---------------- 128x64 bf16 MFMA GEMM core (BK=64, global_load_lds, XOR swizzle) ----------------
static __device__ __forceinline__ void gemm_core_128x64(const u16* __restrict__ A, const u16* __restrict__ B,
                                                        int brow, int bcol, int K,
                                                        u16* ldsA, u16* ldsB, f32x4 acc[4][2]) {
  const int tid = threadIdx.x;
  const int wave = tid >> 6, lane = tid & 63;
  const int wr = wave >> 1, wc = wave & 1;
  const int g = lane >> 4, l15 = lane & 15;

  for (int k0 = 0; k0 < K; k0 += 64) {
#pragma unroll
    for (int li = 0; li < 4; ++li) {
      const int f = li * 256 + wave * 64 + lane;
      const int row = f >> 3;
      const int slot = f & 7;
      const int gcol = ((slot ^ (row & 7)) << 3);
      gload16(A + (size_t)(brow + row) * K + k0 + gcol, ldsA + (size_t)(li * 256 + wave * 64) * 8);
    }
#pragma unroll
    for (int li = 0; li < 2; ++li) {
      const int f = li * 256 + wave * 64 + lane;
      const int row = f >> 3;
      const int slot = f & 7;
      const int gcol = ((slot ^ (row & 7)) << 3);
      gload16(B + (size_t)(bcol + row) * K + k0 + gcol, ldsB + (size_t)(li * 256 + wave * 64) * 8);
    }
    __syncthreads();
    bf16x8 af[4][2], bfr[2][2];
#pragma unroll
    for (int kk = 0; kk < 2; ++kk) {
#pragma unroll
      for (int m = 0; m < 4; ++m) {
        const int rowA = wr * 64 + m * 16 + l15;
        const int chA = (kk * 4 + g) ^ (rowA & 7);
        af[m][kk] = *(const bf16x8*)(ldsA + (size_t)rowA * 64 + chA * 8);
      }
#pragma unroll
      for (int n = 0; n < 2; ++n) {
        const int rowB = wc * 32 + n * 16 + l15;
        const int chB = (kk * 4 + g) ^ (rowB & 7);
        bfr[n][kk] = *(const bf16x8*)(ldsB + (size_t)rowB * 64 + chB * 8);
      }
    }
#pragma unroll
    for (int m = 0; m < 4; ++m)
#pragma unroll
      for (int n = 0; n < 2; ++n)
#pragma unroll
        for (int kk = 0; kk < 2; ++kk)
          acc[m][n] = MFMA16(af[m][kk], bfr[n][kk], acc[m][n]);
    __syncthreads();
  }
}

// ---------------- GEMM1: x @ [Wqkv|W1p|W2p]  (M=2048, N=3200, K=1024), 128x64 tile ----------------
// Q prescale = 0.125 * log2(e); V stored TILED: Vt[h][jt][d][tin] = [h][64][64][32]
__global__ __launch_bounds__(256) void k_gemm_qkvp(const u16* __restrict__ xb, const u16* __restrict__ WB,
                                                   const float* __restrict__ bqkv,
                                                   u16* __restrict__ Qext, u16* __restrict__ Kext,
                                                   u16* __restrict__ Vt, float* __restrict__ P12) {
  __shared__ __align__(16) u16 ldsA[128 * 64];
  __shared__ __align__(16) u16 ldsB[64 * 64];
  const int bid = blockIdx.x;                      // 800 blocks
  const int bn = bid % 50, bm = bid / 50;
  f32x4 acc[4][2];
#pragma unroll
  for (int m = 0; m < 4; ++m)
#pragma unroll
    for (int n = 0; n < 2; ++n) acc[m][n] = (f32x4){0.f, 0.f, 0.f, 0.f};
  gemm_core_128x64(xb, WB, bm * 128, bn * 64, 1024, ldsA, ldsB, acc);

  const int tid = threadIdx.x;
  const int wave = tid >> 6, lane = tid & 63;
  const int wr = wave >> 1, wc = wave & 1;
  const int g = lane >> 4, l15 = lane & 15;
  const int tbase = bm * 128 + wr * 64 + g * 4;
  const int cbase = bn * 64 + wc * 32 + l15;
#pragma unroll
  for (int m = 0; m < 4; ++m) {
#pragma unroll
    for (int n = 0; n < 2; ++n) {
      const int c = cbase + n * 16;
#pragma unroll
      for (int r = 0; r < 4; ++r) {
        const int t = tbase + m * 16 + r;
        float v = acc[m][n][r];
        if (c < 3072) {
          v += bqkv[c];
          const int sub = c >> 10;
          const int rem = c & 1023;
          const int hh = rem >> 6, d = rem & 63;
          if (sub == 0)      Qext[((size_t)hh * 2048 + t) * 96 + d] = f2b(v * 0.18033688f);
          else if (sub == 1) Kext[((size_t)hh * 2048 + t) * 96 + d] = f2b(v);
          else               Vt[(size_t)hh * 131072 + (size_t)(t >> 5) * 2048 + d * 32 + (t & 31)] = f2b(v);
        } else {
          P12[(size_t)t * 128 + (c - 3072)] = v;
        }
      }
    }
  }
}

// ---------------- Plucker lines -> Qext/Kext cols 64..95 ----------------
__global__ __launch_bounds__(256) void k_lines(const float* __restrict__ P12, const float* __restrict__ pscale,
                                               u16* __restrict__ Qext, u16* __restrict__ Kext) {
  const int idx = blockIdx.x * 256 + threadIdx.x;  // 32768 = 2048*16
  const int t = idx >> 4, h = idx & 15;
  const float* p = P12 + (size_t)t * 128;
  const float a0 = p[h * 4 + 0], a1 = p[h * 4 + 1], a2 = p[h * 4 + 2], a3 = p[h * 4 + 3];
  const float b0 = p[64 + h * 4 + 0], b1 = p[64 + h * 4 + 1], b2 = p[64 + h * 4 + 2], b3 = p[64 + h * 4 + 3];
  float L0 = a0 * b1 - a1 * b0;
  float L1 = a0 * b2 - a2 * b0;
  float L2 = a0 * b3 - a3 * b0;
  float L3 = a1 * b2 - a2 * b1;
  float L4 = a1 * b3 - a3 * b1;
  float L5 = a2 * b3 - a3 * b2;
  const float nrm = sqrtf(L0 * L0 + L1 * L1 + L2 * L2 + L3 * L3 + L4 * L4 + L5 * L5);
  const float inv = 1.0f / fmaxf(nrm, 1e-12f);
  L0 *= inv; L1 *= inv; L2 *= inv; L3 *= inv; L4 *= inv; L5 *= inv;
  const float s = pscale[h] * 1.44269504f;  // fold log2(e) into q-side bias
  u16* q = Qext + ((size_t)h * 2048 + t) * 96 + 64;
  u16* k = Kext + ((size_t)h * 2048 + t) * 96 + 64;
  q[0] = f2b(L0 * s); q[1] = f2b(L1 * s); q[2] = f2b(L2 * s);
  q[3] = f2b(L3 * s); q[4] = f2b(L4 * s); q[5] = f2b(L5 * s);
  // Jlines = J6 @ L : [L5, -L4, L3, L2, -L1, L0]
  k[0] = f2b(L5); k[1] = f2b(-L4); k[2] = f2b(L3);
  k[3] = f2b(L2); k[4] = f2b(-L1); k[5] = f2b(L0);
#pragma unroll
  for (int c = 6; c < 32; ++c) { q[c] = 0; k[c] = 0; }
}

// ---------------- fused causal attention: paired dual-stream + pipelined + permlane glue ----------------
// ONE change vs R10: P^T redistribution via v_permlane32_swap + v_permlane16_swap (8 VALU ops)
// instead of 16 ds_bpermute + 8 cndmask. Routing verified equivalent word-for-word.
__global__ __launch_bounds__(64) void k_attn(const u16* __restrict__ Qext, const u16* __restrict__ Kext,
                                             const u16* __restrict__ Vt, u16* __restrict__ AO) {
  const int bid = blockIdx.x;                     // 1024 blocks = 16 heads x 64 pairs
  const int h = bid & 15;
  const int p = bid >> 4;                         // 0..63
  const int lane = threadIdx.x;
  const int g = lane >> 4, l15 = lane & 15;
  const int q0A = p << 4;
  const int q0B = (127 - p) << 4;
  const int qgA = q0A + l15;
  const int qgB = q0B + l15;
  const int sA = (p >> 1) + 1;                    // steps for tile A
  const int sB = ((127 - p) >> 1) + 1;            // steps for tile B (> sA)
  const u16* Qh = Qext + (size_t)h * 2048 * 96;
  const u16* Kh = Kext + (size_t)h * 2048 * 96;
  const u16* Vh = Vt + (size_t)h * 131072;

  bf16x8 aqA[3], aqB[3];
#pragma unroll
  for (int ks = 0; ks < 3; ++ks) {
    aqA[ks] = *(const bf16x8*)(Qh + (size_t)qgA * 96 + ks * 32 + g * 8);
    aqB[ks] = *(const bf16x8*)(Qh + (size_t)qgB * 96 + ks * 32 + g * 8);
  }

  f32x4 accA[4], accB[4];
#pragma unroll
  for (int n = 0; n < 4; ++n) {
    accA[n] = (f32x4){0.f, 0.f, 0.f, 0.f};
    accB[n] = (f32x4){0.f, 0.f, 0.f, 0.f};
  }
  float lA = 0.f, lB = 0.f;

  const u16* Kbase = Kh + (size_t)l15 * 96 + g * 8;
  const u16* Vlane = Vh + (size_t)l15 * 32 + g * 8;   // + jt*2048 + n*512

  bf16x8 kX0[3], kX1[3], kY0[3], kY1[3];
  bf16x8 avX[4], avY[4];
  f32x4 SA0c, SA1c, SB0c, SB1c, SA0n, SA1n, SB0n, SB1n;

  // ---- prologue: K(0)->kX, S(0), K(1)->kY, V(0)->avX
  {
#pragma unroll
    for (int ks = 0; ks < 3; ++ks) {
      kX0[ks] = *(const bf16x8*)(Kbase + ks * 32);
      kX1[ks] = *(const bf16x8*)(Kbase + 16 * 96 + ks * 32);
    }
    SB0c = (f32x4){0.f, 0.f, 0.f, 0.f}; SB1c = SB0c; SA0c = SB0c; SA1c = SB0c;
#pragma unroll
    for (int ks = 0; ks < 3; ++ks) {
      SB0c = MFMA16(kX0[ks], aqB[ks], SB0c);
      SB1c = MFMA16(kX1[ks], aqB[ks], SB1c);
      SA0c = MFMA16(kX0[ks], aqA[ks], SA0c);
      SA1c = MFMA16(kX1[ks], aqA[ks], SA1c);
    }
    const u16* kp = Kbase + (size_t)((1 < sB) ? 1 : 0) * 32 * 96;
#pragma unroll
    for (int ks = 0; ks < 3; ++ks) {
      kY0[ks] = *(const bf16x8*)(kp + ks * 32);
      kY1[ks] = *(const bf16x8*)(kp + 16 * 96 + ks * 32);
    }
#pragma unroll
    for (int n = 0; n < 4; ++n) avX[n] = *(const bf16x8*)(Vlane + n * 512);
  }

#define GLUE(S0, S1, Q0S, QGS, LS, PBS)                                           \
  {                                                                               \
    if (jb + 31 > Q0S) {                                                          \
      _Pragma("unroll")                                                           \
      for (int r = 0; r < 4; ++r) {                                               \
        if (jb + g * 4 + r > QGS) S0[r] = -1e30f;                                 \
        if (jb + 16 + g * 4 + r > QGS) S1[r] = -1e30f;                            \
      }                                                                           \
    }                                                                             \
    _Pragma("unroll")                                                             \
    for (int r = 0; r < 4; ++r) {                                                 \
      S0[r] = exp2fast(S0[r]);                                                    \
      S1[r] = exp2fast(S1[r]);                                                    \
    }                                                                             \
    LS += ((S0[0] + S0[1]) + (S0[2] + S0[3])) + ((S1[0] + S1[1]) + (S1[2] + S1[3])); \
    u32 a0 = pack2(S0[0], S0[1]);                                                 \
    u32 a1 = pack2(S0[2], S0[3]);                                                 \
    u32 b0 = pack2(S1[0], S1[1]);                                                 \
    u32 b1 = pack2(S1[2], S1[3]);                                                 \
    asm("v_permlane32_swap_b32 %0, %1" : "+v"(a0), "+v"(b0));                     \
    asm("v_permlane16_swap_b32 %0, %1" : "+v"(a0), "+v"(b0));                     \
    asm("v_permlane32_swap_b32 %0, %1" : "+v"(a1), "+v"(b1));                     \
    asm("v_permlane16_swap_b32 %0, %1" : "+v"(a1), "+v"(b1));                     \
    PBS.u[0] = a0;                                                                \
    PBS.u[1] = a1;                                                                \
    PBS.u[2] = b0;                                                                \
    PBS.u[3] = b1;                                                                \
  }

  // STEP for iteration jt: S_cur = S(jt) ready; KN holds K(jt+1); KL gets K(jt+2);
  // AVC = V(jt) ready; AVN gets V(jt+1).
#define ATTN_STEP(SA0C, SA1C, SB0C, SB1C, SA0N, SA1N, SB0N, SB1N, KN0, KN1, KL0, KL1, AVC, AVN) \
  {                                                                               \
    const int jb = jt * 32;                                                       \
    const int jn1 = (jt + 1 < sB) ? jt + 1 : jt;                                  \
    const int jn2 = (jt + 2 < sB) ? jt + 2 : jt;                                  \
    /* 1: S(jt+1) from K-regs loaded last step */                                 \
    SB0N = (f32x4){0.f, 0.f, 0.f, 0.f}; SB1N = SB0N;                              \
    __builtin_amdgcn_s_setprio(1);                                                \
    _Pragma("unroll")                                                             \
    for (int ks = 0; ks < 3; ++ks) {                                              \
      SB0N = MFMA16(KN0[ks], aqB[ks], SB0N);                                      \
      SB1N = MFMA16(KN1[ks], aqB[ks], SB1N);                                      \
    }                                                                             \
    if (jt + 1 < sA) {                                                            \
      SA0N = (f32x4){0.f, 0.f, 0.f, 0.f}; SA1N = SA0N;                            \
      _Pragma("unroll")                                                           \
      for (int ks = 0; ks < 3; ++ks) {                                            \
        SA0N = MFMA16(KN0[ks], aqA[ks], SA0N);                                    \
        SA1N = MFMA16(KN1[ks], aqA[ks], SA1N);                                    \
      }                                                                           \
    }                                                                             \
    __builtin_amdgcn_s_setprio(0);                                                \
    /* 2: prefetch K(jt+2) */                                                     \
    const u16* kp = Kbase + (size_t)jn2 * 32 * 96;                                \
    _Pragma("unroll")                                                             \
    for (int ks = 0; ks < 3; ++ks) {                                              \
      KL0[ks] = *(const bf16x8*)(kp + ks * 32);                                   \
      KL1[ks] = *(const bf16x8*)(kp + 16 * 96 + ks * 32);                         \
    }                                                                             \
    /* 3: prefetch V(jt+1) */                                                     \
    _Pragma("unroll")                                                             \
    for (int n = 0; n < 4; ++n)                                                   \
      AVN[n] = *(const bf16x8*)(Vlane + (size_t)jn1 * 2048 + n * 512);            \
    /* 4: GLUE on ready S(jt) */                                                  \
    union { u32 u[4]; bf16x8 bv; } pbB, pbA;                                      \
    GLUE(SB0C, SB1C, q0B, qgB, lB, pbB);                                          \
    const bool actA = (jt < sA);                                                  \
    if (actA) GLUE(SA0C, SA1C, q0A, qgA, lA, pbA);                                \
    /* 5: PV on V loaded last step */                                             \
    __builtin_amdgcn_s_setprio(1);                                                \
    _Pragma("unroll")                                                             \
    for (int n = 0; n < 4; ++n) accB[n] = MFMA16(AVC[n], pbB.bv, accB[n]);        \
    if (actA) {                                                                   \
      _Pragma("unroll")                                                           \
      for (int n = 0; n < 4; ++n) accA[n] = MFMA16(AVC[n], pbA.bv, accA[n]);      \
    }                                                                             \
    __builtin_amdgcn_s_setprio(0);                                                \
  }

  int jt = 0;
  for (;;) {
    ATTN_STEP(SA0c, SA1c, SB0c, SB1c, SA0n, SA1n, SB0n, SB1n, kY0, kY1, kX0, kX1, avX, avY);
    if (++jt >= sB) break;
    ATTN_STEP(SA0n, SA1n, SB0n, SB1n, SA0c, SA1c, SB0c, SB1c, kX0, kX1, kY0, kY1, avY, avX);
    if (++jt >= sB) break;
  }
#undef ATTN_STEP
#undef GLUE

  // epilogue: reduce row-sum partials across the 4 g-groups, normalize, store (both streams)
  lA += __shfl_xor(lA, 16);
  lA += __shfl_xor(lA, 32);
  lB += __shfl_xor(lB, 16);
  lB += __shfl_xor(lB, 32);
  const float invA = 1.0f / lA;
  const float invB = 1.0f / lB;
  u32* dstA = (u32*)(AO + (size_t)qgA * 1024 + h * 64 + g * 4);
  u32* dstB = (u32*)(AO + (size_t)qgB * 1024 + h * 64 + g * 4);
#pragma unroll
  for (int n = 0; n < 4; ++n) {
    dstA[n * 8 + 0] = pack2(accA[n][0] * invA, accA[n][1] * invA);
    dstA[n * 8 + 1] = pack2(accA[n][2] * invA, accA[n][3] * invA);
    dstB[n * 8 + 0] = pack2(accB[n][0] * invB, accB[n][1] * invB);
    dstB[n * 8 + 1] = pack2(accB[n][2] * invB, accB[n][3] * invB);
  }
}

// ---------------- GEMM out: AO @ WoutT + bout  (M=2048, N=1024, K=1024), 128x32 tile ----------------
__global__ __launch_bounds__(256) void k_gemm_out(const u16* __restrict__ AO, const u16* __restrict__ WoT,
                                                  const float* __restrict__ bout, float* __restrict__ out) {
  __shared__ __align__(16) u16 ldsA[128 * 64];
  __shared__ __align__(16) u16 ldsB[32 * 64];
  const int bid = blockIdx.x;                     // 512 blocks = 2/CU
  const int bn = bid & 31, bm = bid >> 5;
  const int tid = threadIdx.x;
  const int wave = tid >> 6, lane = tid & 63;
  const int wr = wave >> 1, wc = wave & 1;
  const int g = lane >> 4, l15 = lane & 15;

  f32x4 acc[4];
#pragma unroll
  for (int m = 0; m < 4; ++m) acc[m] = (f32x4){0.f, 0.f, 0.f, 0.f};

  for (int k0 = 0; k0 < 1024; k0 += 64) {
#pragma unroll
    for (int li = 0; li < 4; ++li) {
      const int f = li * 256 + wave * 64 + lane;
      const int row = f >> 3;
      const int slot = f & 7;
      const int gcol = ((slot ^ (row & 7)) << 3);
      gload16(AO + (size_t)(bm * 128 + row) * 1024 + k0 + gcol, ldsA + (size_t)(li * 256 + wave * 64) * 8);
    }
    {
      const int f = wave * 64 + lane;            // 256 chunks = 32 rows x 64 cols
      const int row = f >> 3;
      const int slot = f & 7;
      const int gcol = ((slot ^ (row & 7)) << 3);
      gload16(WoT + (size_t)(bn * 32 + row) * 1024 + k0 + gcol, ldsB + (size_t)(wave * 64) * 8);
    }
    __syncthreads();
    bf16x8 af[4][2], bfr[2];
#pragma unroll
    for (int kk = 0; kk < 2; ++kk) {
#pragma unroll
      for (int m = 0; m < 4; ++m) {
        const int rowA = wr * 64 + m * 16 + l15;
        const int chA = (kk * 4 + g) ^ (rowA & 7);
        af[m][kk] = *(const bf16x8*)(ldsA + (size_t)rowA * 64 + chA * 8);
      }
      const int rowB = wc * 16 + l15;
      const int chB = (kk * 4 + g) ^ (rowB & 7);
      bfr[kk] = *(const bf16x8*)(ldsB + (size_t)rowB * 64 + chB * 8);
    }
#pragma unroll
    for (int m = 0; m < 4; ++m)
#pragma unroll
      for (int kk = 0; kk < 2; ++kk)
        acc[m] = MFMA16(af[m][kk], bfr[kk], acc[m]);
    __syncthreads();
  }

  const int tbase = bm * 128 + wr * 64 + g * 4;
  const int c = bn * 32 + wc * 16 + l15;
  const float bb = bout[c];
#pragma unroll
  for (int m = 0; m < 4; ++m)
#pragma unroll
    for (int r = 0; r < 4; ++r) {
      const int t = tbase + m * 16 + r;
      out[(size_t)t * 1024 + c] = acc[m][r] + bb;
    }
}

// ---------------- launch ----------------
extern "C" void kernel_launch(void* const* d_in, const int* in_sizes, int n_in,
                              void* d_out, int out_size, void* d_ws, size_t ws_size,
                              hipStream_t stream) {
  const float* x      = (const float*)d_in[0];
  const float* Wqkv   = (const float*)d_in[1];
  const float* bqkv   = (const float*)d_in[2];
  const float* W1p    = (const float*)d_in[3];
  const float* W2p    = (const float*)d_in[4];
  const float* pscale = (const float*)d_in[5];
  const float* Wout   = (const float*)d_in[6];
  const float* bout   = (const float*)d_in[7];
  float* out = (float*)d_out;

  char* ws = (char*)d_ws;
  u16*   WB    = (u16*)(ws + 0);          // [3200][1024] bf16
  u16*   WoT   = (u16*)(ws + 6553600);    // [1024][1024] bf16
  u16*   xb    = (u16*)(ws + 8650752);    // [2048][1024] bf16
  u16*   Qext  = (u16*)(ws + 12845056);   // [16][2048][96] bf16 (q*0.1803 | s*log2e*L | 0)
  u16*   Kext  = (u16*)(ws + 19136512);   // [16][2048][96] bf16 (k | J·L | 0)
  u16*   Vt    = (u16*)(ws + 25427968);   // [16][64][64][32] bf16 (tiled V^T)
  float* P12   = (float*)(ws + 29622272); // [2048][128] f32
  u16*   AO    = (u16*)(ws + 30670848);   // [2048][1024] bf16

  k_prep<<<3584, 256, 0, stream>>>(Wqkv, Wout, W1p, W2p, x, WB, WoT, xb);
  k_gemm_qkvp<<<800, 256, 0, stream>>>(xb, WB, bqkv, Qext, Kext, Vt, P12);
  k_lines<<<128, 256, 0, stream>>>(P12, pscale, Qext, Kext);
  k_attn<<<1024, 64, 0, stream>>>(Qext, Kext, Vt, AO);
  k_gemm_out<<<512, 256, 0, stream>>>(AO, WoT, bout, out);
}